// Round 1
// baseline (2171.466 us; speedup 1.0000x reference)
//
#include <hip/hip_runtime.h>

#define NN 100000
#define NE 1600000

static inline size_t alignup(size_t x) { return (x + 255) & ~(size_t)255; }

// ---------------- degree count ----------------
__global__ void k_deg(const int* __restrict__ dst, int* __restrict__ deg) {
    int i = blockIdx.x * blockDim.x + threadIdx.x;
    int stride = gridDim.x * blockDim.x;
    for (; i < NE; i += stride) atomicAdd(&deg[dst[i]], 1);
}

// ---------------- single-block exclusive scan over NN (+ total) ----------------
__global__ void k_scan(const int* __restrict__ deg, int* __restrict__ row_ptr) {
    __shared__ int sdata[1024];
    __shared__ int s_run;
    int tid = threadIdx.x;
    if (tid == 0) s_run = 0;
    __syncthreads();
    for (int base = 0; base < NN; base += 1024) {
        int i = base + tid;
        int v = (i < NN) ? deg[i] : 0;
        sdata[tid] = v;
        __syncthreads();
        for (int off = 1; off < 1024; off <<= 1) {
            int t = (tid >= off) ? sdata[tid - off] : 0;
            __syncthreads();
            sdata[tid] += t;
            __syncthreads();
        }
        int incl = sdata[tid];
        int run = s_run;
        __syncthreads();
        if (i < NN) row_ptr[i] = run + incl - v;  // exclusive
        if (tid == 1023) s_run = run + incl;
        __syncthreads();
    }
    if (tid == 0) row_ptr[NN] = s_run;
}

// ---------------- cursor init + inv_deg ----------------
__global__ void k_initcur(const int* __restrict__ row_ptr, const int* __restrict__ deg,
                          int* __restrict__ cursor, float* __restrict__ inv_deg) {
    int i = blockIdx.x * blockDim.x + threadIdx.x;
    if (i >= NN) return;
    cursor[i] = row_ptr[i];
    int d = deg[i];
    inv_deg[i] = 1.0f / ((d > 1) ? (float)d : 1.0f);
}

// ---------------- CSR fill (counting sort by dst) ----------------
__global__ void k_fill(const int* __restrict__ src, const int* __restrict__ dst,
                       int* __restrict__ cursor, int* __restrict__ col) {
    int i = blockIdx.x * blockDim.x + threadIdx.x;
    int stride = gridDim.x * blockDim.x;
    for (; i < NE; i += stride) {
        int d = dst[i];
        int p = atomicAdd(&cursor[d], 1);
        col[p] = src[i];
    }
}

// ---------------- GEMM: out[n][m] = A[n][:K] . W[m][:K] + b[m] ----------------
template <int K, int M, bool RELU>
__global__ __launch_bounds__(256) void k_gemm(const float* __restrict__ A,
                                              const float* __restrict__ W,
                                              const float* __restrict__ bias,
                                              float* __restrict__ out) {
    __shared__ float Wt[K * M];  // Wt[k][m]
    int tid = threadIdx.x;
    for (int idx = tid; idx < K * M; idx += 256) {
        int m = idx / K, k = idx % K;
        Wt[k * M + m] = W[idx];
    }
    __syncthreads();
    constexpr int NPB = 256 / M;
    int n = blockIdx.x * NPB + tid / M;
    int m = tid % M;
    if (n >= NN) return;
    const float4* a4 = (const float4*)(A + (long)n * K);
    float acc = bias[m];
    #pragma unroll
    for (int k4 = 0; k4 < K / 4; ++k4) {
        float4 av = a4[k4];
        acc += av.x * Wt[(4 * k4 + 0) * M + m];
        acc += av.y * Wt[(4 * k4 + 1) * M + m];
        acc += av.z * Wt[(4 * k4 + 2) * M + m];
        acc += av.w * Wt[(4 * k4 + 3) * M + m];
    }
    if (RELU) acc = fmaxf(acc, 0.0f);
    out[(long)n * M + m] = acc;
}

// ---------------- fused SAGE linear: out = (agg*inv_deg)@Wl.T + bl + h@Wr.T ----------------
template <int M, bool RELU>
__global__ __launch_bounds__(256) void k_sage_lin(const float* __restrict__ AGG,
                                                  const float* __restrict__ H,
                                                  const float* __restrict__ inv_deg,
                                                  const float* __restrict__ Wl,
                                                  const float* __restrict__ bl,
                                                  const float* __restrict__ Wr,
                                                  float* __restrict__ out) {
    __shared__ float Wlt[64 * M];  // [k][m]
    __shared__ float Wrt[64 * M];
    int tid = threadIdx.x;
    for (int idx = tid; idx < 64 * M; idx += 256) {
        int m = idx / 64, k = idx % 64;
        Wlt[k * M + m] = Wl[idx];
        Wrt[k * M + m] = Wr[idx];
    }
    __syncthreads();
    constexpr int NPB = 256 / M;
    int n = blockIdx.x * NPB + tid / M;
    int m = tid % M;
    if (n >= NN) return;
    const float4* g4 = (const float4*)(AGG + (long)n * 64);
    const float4* h4 = (const float4*)(H + (long)n * 64);
    float s1 = 0.0f, s2 = 0.0f;
    #pragma unroll
    for (int k4 = 0; k4 < 16; ++k4) {
        float4 gv = g4[k4];
        float4 hv = h4[k4];
        s1 += gv.x * Wlt[(4 * k4 + 0) * M + m];
        s1 += gv.y * Wlt[(4 * k4 + 1) * M + m];
        s1 += gv.z * Wlt[(4 * k4 + 2) * M + m];
        s1 += gv.w * Wlt[(4 * k4 + 3) * M + m];
        s2 += hv.x * Wrt[(4 * k4 + 0) * M + m];
        s2 += hv.y * Wrt[(4 * k4 + 1) * M + m];
        s2 += hv.z * Wrt[(4 * k4 + 2) * M + m];
        s2 += hv.w * Wrt[(4 * k4 + 3) * M + m];
    }
    float acc = s1 * inv_deg[n] + s2 + bl[m];
    if (RELU) acc = fmaxf(acc, 0.0f);
    out[(long)n * M + m] = acc;
}

// ---------------- neighbor aggregation: one wave per node, lane = feature ----------------
__global__ __launch_bounds__(256) void k_agg(const float* __restrict__ H,
                                             const int* __restrict__ row_ptr,
                                             const int* __restrict__ col,
                                             float* __restrict__ AGG) {
    int gt = blockIdx.x * blockDim.x + threadIdx.x;
    int n = gt >> 6;
    int f = gt & 63;
    if (n >= NN) return;
    int beg = row_ptr[n], end = row_ptr[n + 1];
    float acc = 0.0f;
    for (int e = beg; e < end; ++e) {
        int s = col[e];
        acc += H[(long)s * 64 + f];
    }
    AGG[(long)n * 64 + f] = acc;
}

// ---------------- row L2 normalize (32 cols), in place ----------------
__global__ __launch_bounds__(256) void k_norm(float* __restrict__ out) {
    int gt = blockIdx.x * blockDim.x + threadIdx.x;
    int n = gt >> 5;
    int c = gt & 31;
    if (n >= NN) return;
    float v = out[(long)n * 32 + c];
    float ss = v * v;
    #pragma unroll
    for (int off = 16; off > 0; off >>= 1) ss += __shfl_xor(ss, off);
    float nrm = fmaxf(sqrtf(ss), 1e-12f);
    out[(long)n * 32 + c] = v / nrm;
}

extern "C" void kernel_launch(void* const* d_in, const int* in_sizes, int n_in,
                              void* d_out, int out_size, void* d_ws, size_t ws_size,
                              hipStream_t stream) {
    const float* x      = (const float*)d_in[0];
    const int*   edges  = (const int*)d_in[1];
    const float* W_pre  = (const float*)d_in[2];
    const float* b_pre  = (const float*)d_in[3];
    const float* Wl1    = (const float*)d_in[4];
    const float* bl1    = (const float*)d_in[5];
    const float* Wr1    = (const float*)d_in[6];
    const float* Wl2    = (const float*)d_in[7];
    const float* bl2    = (const float*)d_in[8];
    const float* Wr2    = (const float*)d_in[9];
    const float* Wl3    = (const float*)d_in[10];
    const float* bl3    = (const float*)d_in[11];
    const float* Wr3    = (const float*)d_in[12];
    float* out = (float*)d_out;

    const int* src = edges;
    const int* dst = edges + NE;

    // workspace carve-up
    char* w = (char*)d_ws;
    int*   deg     = (int*)w;   w += alignup(NN * 4);
    int*   row_ptr = (int*)w;   w += alignup((NN + 1) * 4);
    int*   cursor  = (int*)w;   w += alignup(NN * 4);
    float* inv_deg = (float*)w; w += alignup(NN * 4);
    int*   col     = (int*)w;   w += alignup((size_t)NE * 4);
    float* bufA    = (float*)w; w += alignup((size_t)NN * 64 * 4);
    float* bufB    = (float*)w; w += alignup((size_t)NN * 64 * 4);
    float* bufC    = (float*)w; w += alignup((size_t)NN * 64 * 4);

    hipMemsetAsync(deg, 0, NN * sizeof(int), stream);
    k_deg<<<1024, 256, 0, stream>>>(dst, deg);
    k_scan<<<1, 1024, 0, stream>>>(deg, row_ptr);
    k_initcur<<<(NN + 255) / 256, 256, 0, stream>>>(row_ptr, deg, cursor, inv_deg);
    k_fill<<<1024, 256, 0, stream>>>(src, dst, cursor, col);

    // feature_pre: bufA = x @ W_pre.T + b_pre   [NN,64]
    k_gemm<128, 64, false><<<(NN + 3) / 4, 256, 0, stream>>>(x, W_pre, b_pre, bufA);

    // layer 1: agg(bufA)->bufB ; lin -> bufC (relu)
    k_agg<<<(NN * 64 + 255) / 256, 256, 0, stream>>>(bufA, row_ptr, col, bufB);
    k_sage_lin<64, true><<<(NN + 3) / 4, 256, 0, stream>>>(bufB, bufA, inv_deg, Wl1, bl1, Wr1, bufC);

    // layer 2: agg(bufC)->bufB ; lin -> bufA (relu)
    k_agg<<<(NN * 64 + 255) / 256, 256, 0, stream>>>(bufC, row_ptr, col, bufB);
    k_sage_lin<64, true><<<(NN + 3) / 4, 256, 0, stream>>>(bufB, bufC, inv_deg, Wl2, bl2, Wr2, bufA);

    // layer 3: agg(bufA)->bufB ; lin (M=32, no relu) -> out
    k_agg<<<(NN * 64 + 255) / 256, 256, 0, stream>>>(bufA, row_ptr, col, bufB);
    k_sage_lin<32, false><<<(NN + 7) / 8, 256, 0, stream>>>(bufB, bufA, inv_deg, Wl3, bl3, Wr3, out);

    // final L2 normalize
    k_norm<<<(NN * 32 + 255) / 256, 256, 0, stream>>>(out);
}

// Round 2
// 1420.177 us; speedup vs baseline: 1.5290x; 1.5290x over previous
//
#include <hip/hip_runtime.h>

#define NN 100000
#define NE 1600000
#define NBLK ((NN + 255) / 256)   // 391 scan blocks

static inline size_t alignup(size_t x) { return (x + 255) & ~(size_t)255; }

// ---------------- degree count ----------------
__global__ void k_deg(const int* __restrict__ dst, int* __restrict__ deg) {
    int i = blockIdx.x * blockDim.x + threadIdx.x;
    int stride = gridDim.x * blockDim.x;
    for (; i < NE; i += stride) atomicAdd(&deg[dst[i]], 1);
}

// ---------------- 3-phase scan ----------------
// phase 1: per-block (256) exclusive scan of deg -> row_ptr (block-local), block sums
__global__ __launch_bounds__(256) void k_scan1(const int* __restrict__ deg,
                                               int* __restrict__ row_ptr,
                                               int* __restrict__ bsum) {
    __shared__ int wsum[4];
    int tid = threadIdx.x;
    int i = blockIdx.x * 256 + tid;
    int v = (i < NN) ? deg[i] : 0;
    int lane = tid & 63, w = tid >> 6;
    int incl = v;
    #pragma unroll
    for (int off = 1; off < 64; off <<= 1) {
        int t = __shfl_up(incl, off);
        if (lane >= off) incl += t;
    }
    if (lane == 63) wsum[w] = incl;
    __syncthreads();
    int woff = 0;
    #pragma unroll
    for (int j = 0; j < 4; ++j) woff += (j < w) ? wsum[j] : 0;
    if (i < NN) row_ptr[i] = woff + incl - v;  // block-local exclusive
    if (tid == 255) bsum[blockIdx.x] = woff + incl;
}

// phase 2: single wave scans NBLK block sums -> exclusive offsets + grand total
__global__ __launch_bounds__(64) void k_scan2(int* __restrict__ bsum,
                                              int* __restrict__ boff,
                                              int* __restrict__ row_ptr) {
    int lane = threadIdx.x;
    int run = 0;
    for (int base = 0; base < NBLK; base += 64) {
        int i = base + lane;
        int v = (i < NBLK) ? bsum[i] : 0;
        int incl = v;
        #pragma unroll
        for (int off = 1; off < 64; off <<= 1) {
            int t = __shfl_up(incl, off);
            if (lane >= off) incl += t;
        }
        if (i < NBLK) boff[i] = run + incl - v;
        run += __shfl(incl, 63);
    }
    if (lane == 0) row_ptr[NN] = run;
}

// phase 3: add block offsets; also cursor + inv_deg
__global__ __launch_bounds__(256) void k_scan3(int* __restrict__ row_ptr,
                                               const int* __restrict__ boff,
                                               const int* __restrict__ deg,
                                               int* __restrict__ cursor,
                                               float* __restrict__ inv_deg) {
    int i = blockIdx.x * 256 + threadIdx.x;
    if (i >= NN) return;
    int rp = row_ptr[i] + boff[i >> 8];
    row_ptr[i] = rp;
    cursor[i] = rp;
    int d = deg[i];
    inv_deg[i] = 1.0f / ((d > 1) ? (float)d : 1.0f);
}

// ---------------- CSR fill (counting sort by dst) ----------------
__global__ void k_fill(const int* __restrict__ src, const int* __restrict__ dst,
                       int* __restrict__ cursor, int* __restrict__ col) {
    int i = blockIdx.x * blockDim.x + threadIdx.x;
    int stride = gridDim.x * blockDim.x;
    for (; i < NE; i += stride) {
        int d = dst[i];
        int p = atomicAdd(&cursor[d], 1);
        col[p] = src[i];
    }
}

// ---------------- GEMM: out[n][m] = A[n][:K] . W[m][:K] + b[m], 2 nodes/wave-slot ----------------
template <int K, int M>
__global__ __launch_bounds__(256) void k_gemm(const float* __restrict__ A,
                                              const float* __restrict__ W,
                                              const float* __restrict__ bias,
                                              float* __restrict__ out) {
    constexpr int MP = M + 1;
    __shared__ float Wt[K * MP];  // Wt[k][m], padded stride
    int tid = threadIdx.x;
    for (int idx = tid; idx < K * M; idx += 256) {
        int m = idx / K, k = idx % K;
        Wt[k * MP + m] = W[idx];
    }
    __syncthreads();
    constexpr int NPB = 256 / M;           // node-slots per block
    int slot = tid / M;
    int m = tid % M;
    int n0 = blockIdx.x * (NPB * 2) + slot * 2;
    int n1 = n0 + 1;
    if (n0 >= NN) return;
    const float4* a0 = (const float4*)(A + (long)n0 * K);
    const float4* a1 = (const float4*)(A + (long)n1 * K);
    float acc0 = bias[m], acc1 = acc0;
    #pragma unroll
    for (int k4 = 0; k4 < K / 4; ++k4) {
        float4 v0 = a0[k4];
        float4 v1 = (n1 < NN) ? a1[k4] : make_float4(0.f, 0.f, 0.f, 0.f);
        float w0 = Wt[(4 * k4 + 0) * MP + m];
        float w1 = Wt[(4 * k4 + 1) * MP + m];
        float w2 = Wt[(4 * k4 + 2) * MP + m];
        float w3 = Wt[(4 * k4 + 3) * MP + m];
        acc0 += v0.x * w0 + v0.y * w1 + v0.z * w2 + v0.w * w3;
        acc1 += v1.x * w0 + v1.y * w1 + v1.z * w2 + v1.w * w3;
    }
    out[(long)n0 * M + m] = acc0;
    if (n1 < NN) out[(long)n1 * M + m] = acc1;
}

// ---------------- fused SAGE linear (+optional relu / L2-norm epilogue) ----------------
template <int M, bool RELU, bool NORM>
__global__ __launch_bounds__(256) void k_sage_lin(const float* __restrict__ AGG,
                                                  const float* __restrict__ H,
                                                  const float* __restrict__ inv_deg,
                                                  const float* __restrict__ Wl,
                                                  const float* __restrict__ bl,
                                                  const float* __restrict__ Wr,
                                                  float* __restrict__ out) {
    constexpr int MP = M + 1;
    __shared__ float Wlt[64 * MP];  // [k][m] padded
    __shared__ float Wrt[64 * MP];
    int tid = threadIdx.x;
    for (int idx = tid; idx < 64 * M; idx += 256) {
        int m = idx / 64, k = idx % 64;
        Wlt[k * MP + m] = Wl[idx];
        Wrt[k * MP + m] = Wr[idx];
    }
    __syncthreads();
    constexpr int NPB = 256 / M;
    int slot = tid / M;
    int m = tid % M;
    int n0 = blockIdx.x * (NPB * 2) + slot * 2;
    int n1 = n0 + 1;
    if (n0 >= NN) return;
    bool has1 = (n1 < NN);
    const float4* g0 = (const float4*)(AGG + (long)n0 * 64);
    const float4* h0 = (const float4*)(H + (long)n0 * 64);
    const float4* g1 = (const float4*)(AGG + (long)n1 * 64);
    const float4* h1 = (const float4*)(H + (long)n1 * 64);
    float s1_0 = 0.f, s2_0 = 0.f, s1_1 = 0.f, s2_1 = 0.f;
    #pragma unroll
    for (int k4 = 0; k4 < 16; ++k4) {
        float4 gv0 = g0[k4];
        float4 hv0 = h0[k4];
        float4 gv1 = has1 ? g1[k4] : make_float4(0.f, 0.f, 0.f, 0.f);
        float4 hv1 = has1 ? h1[k4] : make_float4(0.f, 0.f, 0.f, 0.f);
        float wl0 = Wlt[(4 * k4 + 0) * MP + m];
        float wl1 = Wlt[(4 * k4 + 1) * MP + m];
        float wl2 = Wlt[(4 * k4 + 2) * MP + m];
        float wl3 = Wlt[(4 * k4 + 3) * MP + m];
        float wr0 = Wrt[(4 * k4 + 0) * MP + m];
        float wr1 = Wrt[(4 * k4 + 1) * MP + m];
        float wr2 = Wrt[(4 * k4 + 2) * MP + m];
        float wr3 = Wrt[(4 * k4 + 3) * MP + m];
        s1_0 += gv0.x * wl0 + gv0.y * wl1 + gv0.z * wl2 + gv0.w * wl3;
        s2_0 += hv0.x * wr0 + hv0.y * wr1 + hv0.z * wr2 + hv0.w * wr3;
        s1_1 += gv1.x * wl0 + gv1.y * wl1 + gv1.z * wl2 + gv1.w * wl3;
        s2_1 += hv1.x * wr0 + hv1.y * wr1 + hv1.z * wr2 + hv1.w * wr3;
    }
    float acc0 = s1_0 * inv_deg[n0] + s2_0 + bl[m];
    float acc1 = s1_1 * (has1 ? inv_deg[n1] : 0.f) + s2_1 + bl[m];
    if (RELU) { acc0 = fmaxf(acc0, 0.f); acc1 = fmaxf(acc1, 0.f); }
    if (NORM) {
        // M==32: each node's outputs live on a 32-lane half-group; shfl_xor stays inside it
        float ss0 = acc0 * acc0, ss1 = acc1 * acc1;
        #pragma unroll
        for (int off = 16; off > 0; off >>= 1) {
            ss0 += __shfl_xor(ss0, off);
            ss1 += __shfl_xor(ss1, off);
        }
        acc0 /= fmaxf(sqrtf(ss0), 1e-12f);
        acc1 /= fmaxf(sqrtf(ss1), 1e-12f);
    }
    out[(long)n0 * M + m] = acc0;
    if (has1) out[(long)n1 * M + m] = acc1;
}

// ---------------- neighbor aggregation: one wave per node, lane = feature ----------------
__global__ __launch_bounds__(256) void k_agg(const float* __restrict__ H,
                                             const int* __restrict__ row_ptr,
                                             const int* __restrict__ col,
                                             float* __restrict__ AGG) {
    int gt = blockIdx.x * blockDim.x + threadIdx.x;
    int n = gt >> 6;
    int f = gt & 63;
    if (n >= NN) return;
    int beg = row_ptr[n], end = row_ptr[n + 1];
    float acc = 0.0f;
    for (int e = beg; e < end; ++e) {
        int s = col[e];
        acc += H[(long)s * 64 + f];
    }
    AGG[(long)n * 64 + f] = acc;
}

extern "C" void kernel_launch(void* const* d_in, const int* in_sizes, int n_in,
                              void* d_out, int out_size, void* d_ws, size_t ws_size,
                              hipStream_t stream) {
    const float* x      = (const float*)d_in[0];
    const int*   edges  = (const int*)d_in[1];
    const float* W_pre  = (const float*)d_in[2];
    const float* b_pre  = (const float*)d_in[3];
    const float* Wl1    = (const float*)d_in[4];
    const float* bl1    = (const float*)d_in[5];
    const float* Wr1    = (const float*)d_in[6];
    const float* Wl2    = (const float*)d_in[7];
    const float* bl2    = (const float*)d_in[8];
    const float* Wr2    = (const float*)d_in[9];
    const float* Wl3    = (const float*)d_in[10];
    const float* bl3    = (const float*)d_in[11];
    const float* Wr3    = (const float*)d_in[12];
    float* out = (float*)d_out;

    const int* src = edges;
    const int* dst = edges + NE;

    // workspace carve-up
    char* w = (char*)d_ws;
    int*   deg     = (int*)w;   w += alignup(NN * 4);
    int*   row_ptr = (int*)w;   w += alignup((NN + 1) * 4);
    int*   cursor  = (int*)w;   w += alignup(NN * 4);
    float* inv_deg = (float*)w; w += alignup(NN * 4);
    int*   bsum    = (int*)w;   w += alignup(NBLK * 4);
    int*   boff    = (int*)w;   w += alignup(NBLK * 4);
    int*   col     = (int*)w;   w += alignup((size_t)NE * 4);
    float* bufA    = (float*)w; w += alignup((size_t)NN * 64 * 4);
    float* bufB    = (float*)w; w += alignup((size_t)NN * 64 * 4);
    float* bufC    = (float*)w; w += alignup((size_t)NN * 64 * 4);

    hipMemsetAsync(deg, 0, NN * sizeof(int), stream);
    k_deg<<<1024, 256, 0, stream>>>(dst, deg);
    k_scan1<<<NBLK, 256, 0, stream>>>(deg, row_ptr, bsum);
    k_scan2<<<1, 64, 0, stream>>>(bsum, boff, row_ptr);
    k_scan3<<<NBLK, 256, 0, stream>>>(row_ptr, boff, deg, cursor, inv_deg);
    k_fill<<<1024, 256, 0, stream>>>(src, dst, cursor, col);

    // feature_pre: bufA = x @ W_pre.T + b_pre   [NN,64]
    k_gemm<128, 64><<<(NN + 7) / 8, 256, 0, stream>>>(x, W_pre, b_pre, bufA);

    // layer 1: agg(bufA)->bufB ; lin -> bufC (relu)
    k_agg<<<(NN * 64 + 255) / 256, 256, 0, stream>>>(bufA, row_ptr, col, bufB);
    k_sage_lin<64, true, false><<<(NN + 7) / 8, 256, 0, stream>>>(bufB, bufA, inv_deg, Wl1, bl1, Wr1, bufC);

    // layer 2: agg(bufC)->bufB ; lin -> bufA (relu)
    k_agg<<<(NN * 64 + 255) / 256, 256, 0, stream>>>(bufC, row_ptr, col, bufB);
    k_sage_lin<64, true, false><<<(NN + 7) / 8, 256, 0, stream>>>(bufB, bufC, inv_deg, Wl2, bl2, Wr2, bufA);

    // layer 3: agg(bufA)->bufB ; lin (M=32) + fused L2-normalize -> out
    k_agg<<<(NN * 64 + 255) / 256, 256, 0, stream>>>(bufA, row_ptr, col, bufB);
    k_sage_lin<32, false, true><<<(NN + 15) / 16, 256, 0, stream>>>(bufB, bufA, inv_deg, Wl3, bl3, Wr3, out);
}

// Round 3
// 896.595 us; speedup vs baseline: 2.4219x; 1.5840x over previous
//
#include <hip/hip_runtime.h>

#define NN 100000
#define NE 1600000
#define NBLK ((NN + 255) / 256)   // 391 scan blocks

static inline size_t alignup(size_t x) { return (x + 255) & ~(size_t)255; }

// ---------------- degree count ----------------
__global__ void k_deg(const int* __restrict__ dst, int* __restrict__ deg) {
    int i = blockIdx.x * blockDim.x + threadIdx.x;
    int stride = gridDim.x * blockDim.x;
    for (; i < NE; i += stride) atomicAdd(&deg[dst[i]], 1);
}

// ---------------- 3-phase scan ----------------
__global__ __launch_bounds__(256) void k_scan1(const int* __restrict__ deg,
                                               int* __restrict__ row_ptr,
                                               int* __restrict__ bsum) {
    __shared__ int wsum[4];
    int tid = threadIdx.x;
    int i = blockIdx.x * 256 + tid;
    int v = (i < NN) ? deg[i] : 0;
    int lane = tid & 63, w = tid >> 6;
    int incl = v;
    #pragma unroll
    for (int off = 1; off < 64; off <<= 1) {
        int t = __shfl_up(incl, off);
        if (lane >= off) incl += t;
    }
    if (lane == 63) wsum[w] = incl;
    __syncthreads();
    int woff = 0;
    #pragma unroll
    for (int j = 0; j < 4; ++j) woff += (j < w) ? wsum[j] : 0;
    if (i < NN) row_ptr[i] = woff + incl - v;
    if (tid == 255) bsum[blockIdx.x] = woff + incl;
}

__global__ __launch_bounds__(64) void k_scan2(int* __restrict__ bsum,
                                              int* __restrict__ boff,
                                              int* __restrict__ row_ptr) {
    int lane = threadIdx.x;
    int run = 0;
    for (int base = 0; base < NBLK; base += 64) {
        int i = base + lane;
        int v = (i < NBLK) ? bsum[i] : 0;
        int incl = v;
        #pragma unroll
        for (int off = 1; off < 64; off <<= 1) {
            int t = __shfl_up(incl, off);
            if (lane >= off) incl += t;
        }
        if (i < NBLK) boff[i] = run + incl - v;
        run += __shfl(incl, 63);
    }
    if (lane == 0) row_ptr[NN] = run;
}

__global__ __launch_bounds__(256) void k_scan3(int* __restrict__ row_ptr,
                                               const int* __restrict__ boff,
                                               const int* __restrict__ deg,
                                               int* __restrict__ cursor,
                                               float* __restrict__ inv_deg) {
    int i = blockIdx.x * 256 + threadIdx.x;
    if (i >= NN) return;
    int rp = row_ptr[i] + boff[i >> 8];
    row_ptr[i] = rp;
    cursor[i] = rp;
    int d = deg[i];
    inv_deg[i] = 1.0f / ((d > 1) ? (float)d : 1.0f);
}

// ---------------- CSR fill ----------------
__global__ void k_fill(const int* __restrict__ src, const int* __restrict__ dst,
                       int* __restrict__ cursor, int* __restrict__ col) {
    int i = blockIdx.x * blockDim.x + threadIdx.x;
    int stride = gridDim.x * blockDim.x;
    for (; i < NE; i += stride) {
        int d = dst[i];
        int p = atomicAdd(&cursor[d], 1);
        col[p] = src[i];
    }
}

// ---------------- unified tiled GEMM ----------------
// out[n][m] = cat(A1,A2)[n][:K] . cat(W1,W2)[m][:K] + bias[m]  (optional relu)
// Register tile 4n x 4m per thread; A read from global (L1 broadcast);
// W transposed in LDS, padded stride M+4 (conflict-free b128 reads).
template <int K1, int K2, int M, bool RELU>
__global__ __launch_bounds__(256, 4) void k_mm(const float* __restrict__ A1,
                                               const float* __restrict__ A2,
                                               const float* __restrict__ W1,
                                               const float* __restrict__ W2,
                                               const float* __restrict__ bias,
                                               float* __restrict__ out) {
    constexpr int K = K1 + K2;
    constexpr int MP = M + 4;
    constexpr int BN = (M == 64) ? 64 : 128;
    constexpr int NG = BN / 4;          // node groups (lanes)
    __shared__ float Wt[K * MP];        // Wt[k][m]
    int tid = threadIdx.x;
    for (int idx = tid; idx < M * K; idx += 256) {
        int m = idx / K, k = idx % K;
        float v = (k < K1) ? W1[m * K1 + k] : W2[m * K2 + (k - K1)];
        Wt[k * MP + m] = v;
    }
    __syncthreads();

    int ng = tid % NG;
    int mg = tid / NG;
    int m0 = mg * 4;
    long nbase = (long)blockIdx.x * BN;

    int n[4];
    const float4* a1p[4];
    const float4* a2p[4];
    #pragma unroll
    for (int r = 0; r < 4; ++r) {
        n[r] = (int)nbase + ng + NG * r;
        int nc = (n[r] < NN) ? n[r] : (NN - 1);
        a1p[r] = (const float4*)(A1 + (long)nc * K1);
        if (K2 > 0) a2p[r] = (const float4*)(A2 + (long)nc * K2);
    }

    float4 bv = *(const float4*)&bias[m0];
    float acc[4][4];
    #pragma unroll
    for (int r = 0; r < 4; ++r) {
        acc[r][0] = bv.x; acc[r][1] = bv.y; acc[r][2] = bv.z; acc[r][3] = bv.w;
    }

    #pragma unroll 2
    for (int k4 = 0; k4 < K1 / 4; ++k4) {
        float4 w0 = *(const float4*)&Wt[(4 * k4 + 0) * MP + m0];
        float4 w1 = *(const float4*)&Wt[(4 * k4 + 1) * MP + m0];
        float4 w2 = *(const float4*)&Wt[(4 * k4 + 2) * MP + m0];
        float4 w3 = *(const float4*)&Wt[(4 * k4 + 3) * MP + m0];
        #pragma unroll
        for (int r = 0; r < 4; ++r) {
            float4 a = a1p[r][k4];
            acc[r][0] += a.x * w0.x + a.y * w1.x + a.z * w2.x + a.w * w3.x;
            acc[r][1] += a.x * w0.y + a.y * w1.y + a.z * w2.y + a.w * w3.y;
            acc[r][2] += a.x * w0.z + a.y * w1.z + a.z * w2.z + a.w * w3.z;
            acc[r][3] += a.x * w0.w + a.y * w1.w + a.z * w2.w + a.w * w3.w;
        }
    }
    if (K2 > 0) {
        #pragma unroll 2
        for (int k4 = 0; k4 < K2 / 4; ++k4) {
            float4 w0 = *(const float4*)&Wt[(K1 + 4 * k4 + 0) * MP + m0];
            float4 w1 = *(const float4*)&Wt[(K1 + 4 * k4 + 1) * MP + m0];
            float4 w2 = *(const float4*)&Wt[(K1 + 4 * k4 + 2) * MP + m0];
            float4 w3 = *(const float4*)&Wt[(K1 + 4 * k4 + 3) * MP + m0];
            #pragma unroll
            for (int r = 0; r < 4; ++r) {
                float4 a = a2p[r][k4];
                acc[r][0] += a.x * w0.x + a.y * w1.x + a.z * w2.x + a.w * w3.x;
                acc[r][1] += a.x * w0.y + a.y * w1.y + a.z * w2.y + a.w * w3.y;
                acc[r][2] += a.x * w0.z + a.y * w1.z + a.z * w2.z + a.w * w3.z;
                acc[r][3] += a.x * w0.w + a.y * w1.w + a.z * w2.w + a.w * w3.w;
            }
        }
    }

    #pragma unroll
    for (int r = 0; r < 4; ++r) {
        if (n[r] >= NN) continue;
        float4 o;
        o.x = acc[r][0]; o.y = acc[r][1]; o.z = acc[r][2]; o.w = acc[r][3];
        if (RELU) {
            o.x = fmaxf(o.x, 0.f); o.y = fmaxf(o.y, 0.f);
            o.z = fmaxf(o.z, 0.f); o.w = fmaxf(o.w, 0.f);
        }
        *(float4*)(out + (long)n[r] * M + m0) = o;
    }
}

// ---------------- neighbor aggregation (mean): wave per node, lane = feature ----------------
__global__ __launch_bounds__(256) void k_agg(const float* __restrict__ H,
                                             const int* __restrict__ row_ptr,
                                             const int* __restrict__ col,
                                             const float* __restrict__ inv_deg,
                                             float* __restrict__ AGG) {
    int gt = blockIdx.x * blockDim.x + threadIdx.x;
    int n = gt >> 6;
    int f = gt & 63;
    if (n >= NN) return;
    int beg = row_ptr[n], end = row_ptr[n + 1];
    float acc = 0.0f;
    int e = beg;
    for (; e + 3 < end; e += 4) {
        int s0 = col[e], s1 = col[e + 1], s2 = col[e + 2], s3 = col[e + 3];
        float v0 = H[(long)s0 * 64 + f];
        float v1 = H[(long)s1 * 64 + f];
        float v2 = H[(long)s2 * 64 + f];
        float v3 = H[(long)s3 * 64 + f];
        acc += v0 + v1 + v2 + v3;
    }
    for (; e < end; ++e) acc += H[(long)col[e] * 64 + f];
    AGG[(long)n * 64 + f] = acc * inv_deg[n];
}

// ---------------- row L2 normalize (32 cols), in place ----------------
__global__ __launch_bounds__(256) void k_norm(float* __restrict__ out) {
    int gt = blockIdx.x * blockDim.x + threadIdx.x;
    int n = gt >> 5;
    int c = gt & 31;
    if (n >= NN) return;
    float v = out[(long)n * 32 + c];
    float ss = v * v;
    #pragma unroll
    for (int off = 16; off > 0; off >>= 1) ss += __shfl_xor(ss, off);
    float nrm = fmaxf(sqrtf(ss), 1e-12f);
    out[(long)n * 32 + c] = v / nrm;
}

extern "C" void kernel_launch(void* const* d_in, const int* in_sizes, int n_in,
                              void* d_out, int out_size, void* d_ws, size_t ws_size,
                              hipStream_t stream) {
    const float* x      = (const float*)d_in[0];
    const int*   edges  = (const int*)d_in[1];
    const float* W_pre  = (const float*)d_in[2];
    const float* b_pre  = (const float*)d_in[3];
    const float* Wl1    = (const float*)d_in[4];
    const float* bl1    = (const float*)d_in[5];
    const float* Wr1    = (const float*)d_in[6];
    const float* Wl2    = (const float*)d_in[7];
    const float* bl2    = (const float*)d_in[8];
    const float* Wr2    = (const float*)d_in[9];
    const float* Wl3    = (const float*)d_in[10];
    const float* bl3    = (const float*)d_in[11];
    const float* Wr3    = (const float*)d_in[12];
    float* out = (float*)d_out;

    const int* src = edges;
    const int* dst = edges + NE;

    char* w = (char*)d_ws;
    int*   deg     = (int*)w;   w += alignup(NN * 4);
    int*   row_ptr = (int*)w;   w += alignup((NN + 1) * 4);
    int*   cursor  = (int*)w;   w += alignup(NN * 4);
    float* inv_deg = (float*)w; w += alignup(NN * 4);
    int*   bsum    = (int*)w;   w += alignup(NBLK * 4);
    int*   boff    = (int*)w;   w += alignup(NBLK * 4);
    int*   col     = (int*)w;   w += alignup((size_t)NE * 4);
    float* bufA    = (float*)w; w += alignup((size_t)NN * 64 * 4);
    float* bufB    = (float*)w; w += alignup((size_t)NN * 64 * 4);
    float* bufC    = (float*)w; w += alignup((size_t)NN * 64 * 4);

    hipMemsetAsync(deg, 0, NN * sizeof(int), stream);
    k_deg<<<1024, 256, 0, stream>>>(dst, deg);
    k_scan1<<<NBLK, 256, 0, stream>>>(deg, row_ptr, bsum);
    k_scan2<<<1, 64, 0, stream>>>(bsum, boff, row_ptr);
    k_scan3<<<NBLK, 256, 0, stream>>>(row_ptr, boff, deg, cursor, inv_deg);
    k_fill<<<1024, 256, 0, stream>>>(src, dst, cursor, col);

    // feature_pre: bufA = x @ W_pre.T + b_pre   [NN,64]
    k_mm<128, 0, 64, false><<<(NN + 63) / 64, 256, 0, stream>>>(x, nullptr, W_pre, nullptr, b_pre, bufA);

    // layer 1: agg(bufA)->bufB(mean) ; lin(cat(bufB,bufA)) -> bufC (relu)
    k_agg<<<(NN * 64 + 255) / 256, 256, 0, stream>>>(bufA, row_ptr, col, inv_deg, bufB);
    k_mm<64, 64, 64, true><<<(NN + 63) / 64, 256, 0, stream>>>(bufB, bufA, Wl1, Wr1, bl1, bufC);

    // layer 2
    k_agg<<<(NN * 64 + 255) / 256, 256, 0, stream>>>(bufC, row_ptr, col, inv_deg, bufB);
    k_mm<64, 64, 64, true><<<(NN + 63) / 64, 256, 0, stream>>>(bufB, bufC, Wl2, Wr2, bl2, bufA);

    // layer 3 (M=32) -> out, then normalize
    k_agg<<<(NN * 64 + 255) / 256, 256, 0, stream>>>(bufA, row_ptr, col, inv_deg, bufB);
    k_mm<64, 64, 32, false><<<(NN + 127) / 128, 256, 0, stream>>>(bufB, bufA, Wl3, Wr3, bl3, out);

    k_norm<<<(NN * 32 + 255) / 256, 256, 0, stream>>>(out);
}

// Round 4
// 758.482 us; speedup vs baseline: 2.8629x; 1.1821x over previous
//
#include <hip/hip_runtime.h>

#define NN 100000
#define NE 1600000
#define NB 196      // dst buckets (dst >> 9), 512 nodes each
#define NPBK 512    // nodes per bucket

static inline size_t alignup(size_t x) { return (x + 255) & ~(size_t)255; }

// ---------------- bucket count: LDS histogram over 196 buckets ----------------
__global__ __launch_bounds__(256) void k_bcount(const int* __restrict__ dst,
                                                int* __restrict__ bcnt) {
    __shared__ int h[NB];
    int tid = threadIdx.x;
    for (int i = tid; i < NB; i += 256) h[i] = 0;
    __syncthreads();
    int i = blockIdx.x * 256 + tid;
    int stride = gridDim.x * 256;
    for (; i < NE; i += stride) atomicAdd(&h[dst[i] >> 9], 1);
    __syncthreads();
    for (int i2 = tid; i2 < NB; i2 += 256) {
        int c = h[i2];
        if (c) atomicAdd(&bcnt[i2], c);
    }
}

// ---------------- bucket scan (1 block): bases + cursors ----------------
__global__ __launch_bounds__(256) void k_bscan(const int* __restrict__ bcnt,
                                               int* __restrict__ bbase,
                                               int* __restrict__ bcur,
                                               int* __restrict__ row_ptr) {
    __shared__ int tmp[256];
    int tid = threadIdx.x;
    int v = (tid < NB) ? bcnt[tid] : 0;
    tmp[tid] = v;
    __syncthreads();
    for (int off = 1; off < 256; off <<= 1) {
        int t = (tid >= off) ? tmp[tid - off] : 0;
        __syncthreads();
        tmp[tid] += t;
        __syncthreads();
    }
    int excl = tmp[tid] - v;
    if (tid < NB) { bbase[tid] = excl; bcur[tid] = excl; }
    if (tid == 0) row_ptr[NN] = NE;
}

// ---------------- bucket scatter: pack (dstlocal,src), bucket-contiguous writes ----------------
#define EPT 16   // edges per thread; block chunk = 4096
__global__ __launch_bounds__(256) void k_bscatter(const int* __restrict__ src,
                                                  const int* __restrict__ dst,
                                                  int* __restrict__ bcur,
                                                  unsigned* __restrict__ ebuf) {
    __shared__ int h[NB], base[NB], pos[NB];
    int tid = threadIdx.x;
    for (int i = tid; i < NB; i += 256) h[i] = 0;
    __syncthreads();
    long e0 = (long)blockIdx.x * (256 * EPT);
    unsigned packed[EPT];
    int bk[EPT];
    #pragma unroll
    for (int j = 0; j < EPT; ++j) {
        long e = e0 + (long)j * 256 + tid;
        if (e < NE) {
            int s = src[e], d = dst[e];
            bk[j] = d >> 9;
            packed[j] = ((unsigned)(d & 511) << 17) | (unsigned)s;  // src < 2^17
            atomicAdd(&h[bk[j]], 1);
        } else bk[j] = -1;
    }
    __syncthreads();
    for (int i = tid; i < NB; i += 256) {
        int c = h[i];
        base[i] = c ? atomicAdd(&bcur[i], c) : 0;
        pos[i] = 0;
    }
    __syncthreads();
    #pragma unroll
    for (int j = 0; j < EPT; ++j) {
        if (bk[j] >= 0) {
            int p = atomicAdd(&pos[bk[j]], 1);
            ebuf[base[bk[j]] + p] = packed[j];
        }
    }
}

// ---------------- per-bucket CSR: hist + scan -> row_ptr/inv_deg, scatter col ----------------
__global__ __launch_bounds__(256) void k_bcsr(const unsigned* __restrict__ ebuf,
                                              const int* __restrict__ bbase,
                                              int* __restrict__ row_ptr,
                                              float* __restrict__ inv_deg,
                                              int* __restrict__ col) {
    __shared__ int h[NPBK];
    __shared__ int psum[256];
    int b = blockIdx.x;
    int tid = threadIdx.x;
    int begin = bbase[b];
    int end = (b + 1 < NB) ? bbase[b + 1] : NE;
    for (int i = tid; i < NPBK; i += 256) h[i] = 0;
    __syncthreads();
    for (int e = begin + tid; e < end; e += 256) atomicAdd(&h[ebuf[e] >> 17], 1);
    __syncthreads();
    // pairwise scan: thread t owns nodes 2t, 2t+1
    int a0 = h[2 * tid], a1 = h[2 * tid + 1];
    psum[tid] = a0 + a1;
    __syncthreads();
    for (int off = 1; off < 256; off <<= 1) {
        int t = (tid >= off) ? psum[tid - off] : 0;
        __syncthreads();
        psum[tid] += t;
        __syncthreads();
    }
    int pexcl = psum[tid] - (a0 + a1);
    int eo0 = pexcl, eo1 = pexcl + a0;
    int n0 = b * NPBK + 2 * tid, n1 = n0 + 1;
    if (n0 < NN) { row_ptr[n0] = begin + eo0; inv_deg[n0] = 1.0f / (float)((a0 > 1) ? a0 : 1); }
    if (n1 < NN) { row_ptr[n1] = begin + eo1; inv_deg[n1] = 1.0f / (float)((a1 > 1) ? a1 : 1); }
    __syncthreads();
    h[2 * tid] = eo0;        // reuse h as local cursors
    h[2 * tid + 1] = eo1;
    __syncthreads();
    for (int e = begin + tid; e < end; e += 256) {
        unsigned p = ebuf[e];
        int dl = p >> 17;
        int s = (int)(p & 0x1FFFFu);
        int q = atomicAdd(&h[dl], 1);
        col[begin + q] = s;
    }
}

// ---------------- unified tiled GEMM (+optional relu, +optional fused L2-norm) ----------------
template <int K1, int K2, int M, bool RELU, bool NORM>
__global__ __launch_bounds__(256, 4) void k_mm(const float* __restrict__ A1,
                                               const float* __restrict__ A2,
                                               const float* __restrict__ W1,
                                               const float* __restrict__ W2,
                                               const float* __restrict__ bias,
                                               float* __restrict__ out) {
    constexpr int K = K1 + K2;
    constexpr int MP = M + 4;
    constexpr int BN = (M == 64) ? 64 : 128;
    constexpr int NG = BN / 4;
    __shared__ float Wt[K * MP];
    __shared__ float ssq[BN];
    int tid = threadIdx.x;
    for (int idx = tid; idx < M * K; idx += 256) {
        int m = idx / K, k = idx % K;
        float v = (k < K1) ? W1[m * K1 + k] : W2[m * K2 + (k - K1)];
        Wt[k * MP + m] = v;
    }
    if (NORM) { for (int i = tid; i < BN; i += 256) ssq[i] = 0.0f; }
    __syncthreads();

    int ng = tid % NG;
    int mg = tid / NG;
    int m0 = mg * 4;
    long nbase = (long)blockIdx.x * BN;

    int n[4];
    const float4* a1p[4];
    const float4* a2p[4];
    #pragma unroll
    for (int r = 0; r < 4; ++r) {
        n[r] = (int)nbase + ng + NG * r;
        int nc = (n[r] < NN) ? n[r] : (NN - 1);
        a1p[r] = (const float4*)(A1 + (long)nc * K1);
        if (K2 > 0) a2p[r] = (const float4*)(A2 + (long)nc * K2);
    }

    float4 bv = *(const float4*)&bias[m0];
    float acc[4][4];
    #pragma unroll
    for (int r = 0; r < 4; ++r) {
        acc[r][0] = bv.x; acc[r][1] = bv.y; acc[r][2] = bv.z; acc[r][3] = bv.w;
    }

    #pragma unroll 2
    for (int k4 = 0; k4 < K1 / 4; ++k4) {
        float4 w0 = *(const float4*)&Wt[(4 * k4 + 0) * MP + m0];
        float4 w1 = *(const float4*)&Wt[(4 * k4 + 1) * MP + m0];
        float4 w2 = *(const float4*)&Wt[(4 * k4 + 2) * MP + m0];
        float4 w3 = *(const float4*)&Wt[(4 * k4 + 3) * MP + m0];
        #pragma unroll
        for (int r = 0; r < 4; ++r) {
            float4 a = a1p[r][k4];
            acc[r][0] += a.x * w0.x + a.y * w1.x + a.z * w2.x + a.w * w3.x;
            acc[r][1] += a.x * w0.y + a.y * w1.y + a.z * w2.y + a.w * w3.y;
            acc[r][2] += a.x * w0.z + a.y * w1.z + a.z * w2.z + a.w * w3.z;
            acc[r][3] += a.x * w0.w + a.y * w1.w + a.z * w2.w + a.w * w3.w;
        }
    }
    if (K2 > 0) {
        #pragma unroll 2
        for (int k4 = 0; k4 < K2 / 4; ++k4) {
            float4 w0 = *(const float4*)&Wt[(K1 + 4 * k4 + 0) * MP + m0];
            float4 w1 = *(const float4*)&Wt[(K1 + 4 * k4 + 1) * MP + m0];
            float4 w2 = *(const float4*)&Wt[(K1 + 4 * k4 + 2) * MP + m0];
            float4 w3 = *(const float4*)&Wt[(K1 + 4 * k4 + 3) * MP + m0];
            #pragma unroll
            for (int r = 0; r < 4; ++r) {
                float4 a = a2p[r][k4];
                acc[r][0] += a.x * w0.x + a.y * w1.x + a.z * w2.x + a.w * w3.x;
                acc[r][1] += a.x * w0.y + a.y * w1.y + a.z * w2.y + a.w * w3.y;
                acc[r][2] += a.x * w0.z + a.y * w1.z + a.z * w2.z + a.w * w3.z;
                acc[r][3] += a.x * w0.w + a.y * w1.w + a.z * w2.w + a.w * w3.w;
            }
        }
    }

    if (RELU) {
        #pragma unroll
        for (int r = 0; r < 4; ++r)
            #pragma unroll
            for (int j = 0; j < 4; ++j) acc[r][j] = fmaxf(acc[r][j], 0.0f);
    }

    if (NORM) {
        #pragma unroll
        for (int r = 0; r < 4; ++r) {
            float s = acc[r][0] * acc[r][0] + acc[r][1] * acc[r][1]
                    + acc[r][2] * acc[r][2] + acc[r][3] * acc[r][3];
            atomicAdd(&ssq[ng + NG * r], s);
        }
        __syncthreads();
    }

    #pragma unroll
    for (int r = 0; r < 4; ++r) {
        if (n[r] >= NN) continue;
        float4 o;
        o.x = acc[r][0]; o.y = acc[r][1]; o.z = acc[r][2]; o.w = acc[r][3];
        if (NORM) {
            float sc = 1.0f / fmaxf(sqrtf(ssq[ng + NG * r]), 1e-12f);
            o.x *= sc; o.y *= sc; o.z *= sc; o.w *= sc;
        }
        *(float4*)(out + (long)n[r] * M + m0) = o;
    }
}

// ---------------- neighbor aggregation (mean): wave per node, lane = feature ----------------
__global__ __launch_bounds__(256) void k_agg(const float* __restrict__ H,
                                             const int* __restrict__ row_ptr,
                                             const int* __restrict__ col,
                                             const float* __restrict__ inv_deg,
                                             float* __restrict__ AGG) {
    int gt = blockIdx.x * blockDim.x + threadIdx.x;
    int n = gt >> 6;
    int f = gt & 63;
    if (n >= NN) return;
    int beg = row_ptr[n], end = row_ptr[n + 1];
    float acc = 0.0f;
    int e = beg;
    for (; e + 3 < end; e += 4) {
        int s0 = col[e], s1 = col[e + 1], s2 = col[e + 2], s3 = col[e + 3];
        float v0 = H[(long)s0 * 64 + f];
        float v1 = H[(long)s1 * 64 + f];
        float v2 = H[(long)s2 * 64 + f];
        float v3 = H[(long)s3 * 64 + f];
        acc += v0 + v1 + v2 + v3;
    }
    for (; e < end; ++e) acc += H[(long)col[e] * 64 + f];
    AGG[(long)n * 64 + f] = acc * inv_deg[n];
}

extern "C" void kernel_launch(void* const* d_in, const int* in_sizes, int n_in,
                              void* d_out, int out_size, void* d_ws, size_t ws_size,
                              hipStream_t stream) {
    const float* x      = (const float*)d_in[0];
    const int*   edges  = (const int*)d_in[1];
    const float* W_pre  = (const float*)d_in[2];
    const float* b_pre  = (const float*)d_in[3];
    const float* Wl1    = (const float*)d_in[4];
    const float* bl1    = (const float*)d_in[5];
    const float* Wr1    = (const float*)d_in[6];
    const float* Wl2    = (const float*)d_in[7];
    const float* bl2    = (const float*)d_in[8];
    const float* Wr2    = (const float*)d_in[9];
    const float* Wl3    = (const float*)d_in[10];
    const float* bl3    = (const float*)d_in[11];
    const float* Wr3    = (const float*)d_in[12];
    float* out = (float*)d_out;

    const int* src = edges;
    const int* dst = edges + NE;

    char* w = (char*)d_ws;
    int*      row_ptr = (int*)w;      w += alignup((NN + 1) * 4);
    float*    inv_deg = (float*)w;    w += alignup(NN * 4);
    int*      bcnt    = (int*)w;      w += alignup(NB * 4);
    int*      bbase   = (int*)w;      w += alignup(NB * 4);
    int*      bcur    = (int*)w;      w += alignup(NB * 4);
    unsigned* ebuf    = (unsigned*)w; w += alignup((size_t)NE * 4);
    int*      col     = (int*)w;      w += alignup((size_t)NE * 4);
    float*    bufA    = (float*)w;    w += alignup((size_t)NN * 64 * 4);
    float*    bufB    = (float*)w;    w += alignup((size_t)NN * 64 * 4);
    float*    bufC    = (float*)w;    w += alignup((size_t)NN * 64 * 4);

    // ---- CSR build (bucketed counting sort) ----
    hipMemsetAsync(bcnt, 0, NB * sizeof(int), stream);
    k_bcount<<<1024, 256, 0, stream>>>(dst, bcnt);
    k_bscan<<<1, 256, 0, stream>>>(bcnt, bbase, bcur, row_ptr);
    k_bscatter<<<(NE + 4095) / 4096, 256, 0, stream>>>(src, dst, bcur, ebuf);
    k_bcsr<<<NB, 256, 0, stream>>>(ebuf, bbase, row_ptr, inv_deg, col);

    // ---- feature_pre: bufA = x @ W_pre.T + b_pre ----
    k_mm<128, 0, 64, false, false><<<(NN + 63) / 64, 256, 0, stream>>>(x, nullptr, W_pre, nullptr, b_pre, bufA);

    // ---- layer 1 ----
    k_agg<<<(NN * 64 + 255) / 256, 256, 0, stream>>>(bufA, row_ptr, col, inv_deg, bufB);
    k_mm<64, 64, 64, true, false><<<(NN + 63) / 64, 256, 0, stream>>>(bufB, bufA, Wl1, Wr1, bl1, bufC);

    // ---- layer 2 ----
    k_agg<<<(NN * 64 + 255) / 256, 256, 0, stream>>>(bufC, row_ptr, col, inv_deg, bufB);
    k_mm<64, 64, 64, true, false><<<(NN + 63) / 64, 256, 0, stream>>>(bufB, bufC, Wl2, Wr2, bl2, bufA);

    // ---- layer 3 + fused L2 normalize ----
    k_agg<<<(NN * 64 + 255) / 256, 256, 0, stream>>>(bufA, row_ptr, col, inv_deg, bufB);
    k_mm<64, 64, 32, false, true><<<(NN + 127) / 128, 256, 0, stream>>>(bufB, bufA, Wl3, Wr3, bl3, out);
}

// Round 7
// 538.311 us; speedup vs baseline: 4.0338x; 1.4090x over previous
//
#include <hip/hip_runtime.h>

#define NN 100000
#define NE 1600000
#define NB 196      // dst buckets (dst >> 9), 512 nodes each
#define NPBK 512    // nodes per bucket

static inline size_t alignup(size_t x) { return (x + 255) & ~(size_t)255; }

// ---------------- bucket count: LDS histogram over 196 buckets ----------------
__global__ __launch_bounds__(256) void k_bcount(const int* __restrict__ dst,
                                                int* __restrict__ bcnt) {
    __shared__ int h[NB];
    int tid = threadIdx.x;
    for (int i = tid; i < NB; i += 256) h[i] = 0;
    __syncthreads();
    int i = blockIdx.x * 256 + tid;
    int stride = gridDim.x * 256;
    for (; i < NE; i += stride) atomicAdd(&h[dst[i] >> 9], 1);
    __syncthreads();
    for (int i2 = tid; i2 < NB; i2 += 256) {
        int c = h[i2];
        if (c) atomicAdd(&bcnt[i2], c);
    }
}

// ---------------- bucket scan (1 block): bases + cursors ----------------
__global__ __launch_bounds__(256) void k_bscan(const int* __restrict__ bcnt,
                                               int* __restrict__ bbase,
                                               int* __restrict__ bcur,
                                               int* __restrict__ row_ptr) {
    __shared__ int tmp[256];
    int tid = threadIdx.x;
    int v = (tid < NB) ? bcnt[tid] : 0;
    tmp[tid] = v;
    __syncthreads();
    for (int off = 1; off < 256; off <<= 1) {
        int t = (tid >= off) ? tmp[tid - off] : 0;
        __syncthreads();
        tmp[tid] += t;
        __syncthreads();
    }
    int excl = tmp[tid] - v;
    if (tid < NB) { bbase[tid] = excl; bcur[tid] = excl; }
    if (tid == 0) row_ptr[NN] = NE;
}

// ---------------- bucket scatter: pack (dstlocal,src), bucket-contiguous writes ----------------
#define EPT 16   // edges per thread; block chunk = 4096
__global__ __launch_bounds__(256) void k_bscatter(const int* __restrict__ src,
                                                  const int* __restrict__ dst,
                                                  int* __restrict__ bcur,
                                                  unsigned* __restrict__ ebuf) {
    __shared__ int h[NB], base[NB], pos[NB];
    int tid = threadIdx.x;
    for (int i = tid; i < NB; i += 256) h[i] = 0;
    __syncthreads();
    long e0 = (long)blockIdx.x * (256 * EPT);
    unsigned packed[EPT];
    int bk[EPT];
    #pragma unroll
    for (int j = 0; j < EPT; ++j) {
        long e = e0 + (long)j * 256 + tid;
        if (e < NE) {
            int s = src[e], d = dst[e];
            bk[j] = d >> 9;
            packed[j] = ((unsigned)(d & 511) << 17) | (unsigned)s;  // src < 2^17
            atomicAdd(&h[bk[j]], 1);
        } else bk[j] = -1;
    }
    __syncthreads();
    for (int i = tid; i < NB; i += 256) {
        int c = h[i];
        base[i] = c ? atomicAdd(&bcur[i], c) : 0;
        pos[i] = 0;
    }
    __syncthreads();
    #pragma unroll
    for (int j = 0; j < EPT; ++j) {
        if (bk[j] >= 0) {
            int p = atomicAdd(&pos[bk[j]], 1);
            ebuf[base[bk[j]] + p] = packed[j];
        }
    }
}

// ---------------- per-bucket CSR: hist + scan -> row_ptr/inv_deg, scatter col ----------------
__global__ __launch_bounds__(256) void k_bcsr(const unsigned* __restrict__ ebuf,
                                              const int* __restrict__ bbase,
                                              int* __restrict__ row_ptr,
                                              float* __restrict__ inv_deg,
                                              int* __restrict__ col) {
    __shared__ int h[NPBK];
    __shared__ int psum[256];
    int b = blockIdx.x;
    int tid = threadIdx.x;
    int begin = bbase[b];
    int end = (b + 1 < NB) ? bbase[b + 1] : NE;
    for (int i = tid; i < NPBK; i += 256) h[i] = 0;
    __syncthreads();
    for (int e = begin + tid; e < end; e += 256) atomicAdd(&h[ebuf[e] >> 17], 1);
    __syncthreads();
    int a0 = h[2 * tid], a1 = h[2 * tid + 1];
    psum[tid] = a0 + a1;
    __syncthreads();
    for (int off = 1; off < 256; off <<= 1) {
        int t = (tid >= off) ? psum[tid - off] : 0;
        __syncthreads();
        psum[tid] += t;
        __syncthreads();
    }
    int pexcl = psum[tid] - (a0 + a1);
    int eo0 = pexcl, eo1 = pexcl + a0;
    int n0 = b * NPBK + 2 * tid, n1 = n0 + 1;
    if (n0 < NN) { row_ptr[n0] = begin + eo0; inv_deg[n0] = 1.0f / (float)((a0 > 1) ? a0 : 1); }
    if (n1 < NN) { row_ptr[n1] = begin + eo1; inv_deg[n1] = 1.0f / (float)((a1 > 1) ? a1 : 1); }
    __syncthreads();
    h[2 * tid] = eo0;
    h[2 * tid + 1] = eo1;
    __syncthreads();
    for (int e = begin + tid; e < end; e += 256) {
        unsigned p = ebuf[e];
        int dl = p >> 17;
        int s = (int)(p & 0x1FFFFu);
        int q = atomicAdd(&h[dl], 1);
        col[begin + q] = s;
    }
}

// ---------------- LDS-staged tiled GEMM ----------------
// out[n][m] = cat(A1,A2)[n][:K] . cat(W1,W2)[m][:K] + bias[m]  (+relu / +L2-norm)
// BN=64 nodes per block; A tiles staged in LDS via coalesced row loads; weights
// transposed in LDS (stride M+4). Register tile R x 4 per thread.
template <int K1, int K2, int M, bool RELU, bool NORM>
__global__ __launch_bounds__(256, 2) void k_mm(const float* __restrict__ A1,
                                               const float* __restrict__ A2,
                                               const float* __restrict__ W1,
                                               const float* __restrict__ W2,
                                               const float* __restrict__ bias,
                                               float* __restrict__ out) {
    constexpr int K = K1 + K2;
    constexpr int MP = M + 4;
    constexpr int BN = 64;
    constexpr int MG = M / 4;          // m-groups (16 or 8)
    constexpr int NG = 256 / MG;       // node lanes (16 or 32)
    constexpr int R  = BN / NG;        // rows per thread (4 or 2)
    constexpr int S1 = K1 + 4;         // At1 row stride
    constexpr int S2 = (K2 > 0 ? K2 : 1) + 4;

    __shared__ float At1[BN * S1];
    __shared__ float At2[(K2 > 0) ? BN * S2 : 1];
    __shared__ float Wt[K * MP];
    __shared__ float ssq[NORM ? BN : 1];

    int tid = threadIdx.x;
    long nbase = (long)blockIdx.x * BN;

    // ---- stage weights: Wt[k][m] ----
    for (int idx = tid; idx < M * K; idx += 256) {
        int m = idx / K, k = idx % K;
        float v = (k < K1) ? W1[m * K1 + k] : W2[m * K2 + (k - K1)];
        Wt[k * MP + m] = v;
    }
    // ---- stage A1 tile (coalesced: consecutive tid = consecutive 16B in a row) ----
    for (int i = tid; i < BN * (K1 / 4); i += 256) {
        int row = i / (K1 / 4);
        int c4 = i % (K1 / 4);
        long n = nbase + row;
        float4 v = make_float4(0.f, 0.f, 0.f, 0.f);
        if (n < NN) v = *(const float4*)(A1 + n * K1 + c4 * 4);
        *(float4*)&At1[row * S1 + c4 * 4] = v;
    }
    if (K2 > 0) {
        for (int i = tid; i < BN * (K2 / 4); i += 256) {
            int row = i / (K2 / 4);
            int c4 = i % (K2 / 4);
            long n = nbase + row;
            float4 v = make_float4(0.f, 0.f, 0.f, 0.f);
            if (n < NN) v = *(const float4*)(A2 + n * K2 + c4 * 4);
            *(float4*)&At2[row * S2 + c4 * 4] = v;
        }
    }
    if (NORM) { for (int i = tid; i < BN; i += 256) ssq[i] = 0.0f; }
    __syncthreads();

    int ng = tid % NG;
    int mg = tid / NG;
    int m0 = mg * 4;

    float4 bv = *(const float4*)&bias[m0];
    float acc[R][4];
    #pragma unroll
    for (int r = 0; r < R; ++r) {
        acc[r][0] = bv.x; acc[r][1] = bv.y; acc[r][2] = bv.z; acc[r][3] = bv.w;
    }

    #pragma unroll 4
    for (int k4 = 0; k4 < K1 / 4; ++k4) {
        float4 w0 = *(const float4*)&Wt[(4 * k4 + 0) * MP + m0];
        float4 w1 = *(const float4*)&Wt[(4 * k4 + 1) * MP + m0];
        float4 w2 = *(const float4*)&Wt[(4 * k4 + 2) * MP + m0];
        float4 w3 = *(const float4*)&Wt[(4 * k4 + 3) * MP + m0];
        #pragma unroll
        for (int r = 0; r < R; ++r) {
            float4 a = *(const float4*)&At1[(ng + NG * r) * S1 + 4 * k4];
            acc[r][0] += a.x * w0.x + a.y * w1.x + a.z * w2.x + a.w * w3.x;
            acc[r][1] += a.x * w0.y + a.y * w1.y + a.z * w2.y + a.w * w3.y;
            acc[r][2] += a.x * w0.z + a.y * w1.z + a.z * w2.z + a.w * w3.z;
            acc[r][3] += a.x * w0.w + a.y * w1.w + a.z * w2.w + a.w * w3.w;
        }
    }
    if (K2 > 0) {
        #pragma unroll 4
        for (int k4 = 0; k4 < K2 / 4; ++k4) {
            float4 w0 = *(const float4*)&Wt[(K1 + 4 * k4 + 0) * MP + m0];
            float4 w1 = *(const float4*)&Wt[(K1 + 4 * k4 + 1) * MP + m0];
            float4 w2 = *(const float4*)&Wt[(K1 + 4 * k4 + 2) * MP + m0];
            float4 w3 = *(const float4*)&Wt[(K1 + 4 * k4 + 3) * MP + m0];
            #pragma unroll
            for (int r = 0; r < R; ++r) {
                float4 a = *(const float4*)&At2[(ng + NG * r) * S2 + 4 * k4];
                acc[r][0] += a.x * w0.x + a.y * w1.x + a.z * w2.x + a.w * w3.x;
                acc[r][1] += a.x * w0.y + a.y * w1.y + a.z * w2.y + a.w * w3.y;
                acc[r][2] += a.x * w0.z + a.y * w1.z + a.z * w2.z + a.w * w3.z;
                acc[r][3] += a.x * w0.w + a.y * w1.w + a.z * w2.w + a.w * w3.w;
            }
        }
    }

    if (RELU) {
        #pragma unroll
        for (int r = 0; r < R; ++r)
            #pragma unroll
            for (int j = 0; j < 4; ++j) acc[r][j] = fmaxf(acc[r][j], 0.0f);
    }

    if (NORM) {
        #pragma unroll
        for (int r = 0; r < R; ++r) {
            float s = acc[r][0] * acc[r][0] + acc[r][1] * acc[r][1]
                    + acc[r][2] * acc[r][2] + acc[r][3] * acc[r][3];
            atomicAdd(&ssq[ng + NG * r], s);
        }
        __syncthreads();
    }

    #pragma unroll
    for (int r = 0; r < R; ++r) {
        long n = nbase + ng + NG * r;
        if (n >= NN) continue;
        float4 o;
        o.x = acc[r][0]; o.y = acc[r][1]; o.z = acc[r][2]; o.w = acc[r][3];
        if (NORM) {
            float sc = 1.0f / fmaxf(sqrtf(ssq[ng + NG * r]), 1e-12f);
            o.x *= sc; o.y *= sc; o.z *= sc; o.w *= sc;
        }
        *(float4*)(out + n * M + m0) = o;
    }
}

// ---------------- neighbor aggregation (mean): wave per node, lane = feature ----------------
__global__ __launch_bounds__(256) void k_agg(const float* __restrict__ H,
                                             const int* __restrict__ row_ptr,
                                             const int* __restrict__ col,
                                             const float* __restrict__ inv_deg,
                                             float* __restrict__ AGG) {
    int gt = blockIdx.x * blockDim.x + threadIdx.x;
    int n = gt >> 6;
    int f = gt & 63;
    if (n >= NN) return;
    int beg = row_ptr[n], end = row_ptr[n + 1];
    float acc = 0.0f;
    int e = beg;
    for (; e + 3 < end; e += 4) {
        int s0 = col[e], s1 = col[e + 1], s2 = col[e + 2], s3 = col[e + 3];
        float v0 = H[(long)s0 * 64 + f];
        float v1 = H[(long)s1 * 64 + f];
        float v2 = H[(long)s2 * 64 + f];
        float v3 = H[(long)s3 * 64 + f];
        acc += v0 + v1 + v2 + v3;
    }
    for (; e < end; ++e) acc += H[(long)col[e] * 64 + f];
    AGG[(long)n * 64 + f] = acc * inv_deg[n];
}

extern "C" void kernel_launch(void* const* d_in, const int* in_sizes, int n_in,
                              void* d_out, int out_size, void* d_ws, size_t ws_size,
                              hipStream_t stream) {
    const float* x      = (const float*)d_in[0];
    const int*   edges  = (const int*)d_in[1];
    const float* W_pre  = (const float*)d_in[2];
    const float* b_pre  = (const float*)d_in[3];
    const float* Wl1    = (const float*)d_in[4];
    const float* bl1    = (const float*)d_in[5];
    const float* Wr1    = (const float*)d_in[6];
    const float* Wl2    = (const float*)d_in[7];
    const float* bl2    = (const float*)d_in[8];
    const float* Wr2    = (const float*)d_in[9];
    const float* Wl3    = (const float*)d_in[10];
    const float* bl3    = (const float*)d_in[11];
    const float* Wr3    = (const float*)d_in[12];
    float* out = (float*)d_out;

    const int* src = edges;
    const int* dst = edges + NE;

    char* w = (char*)d_ws;
    int*      row_ptr = (int*)w;      w += alignup((NN + 1) * 4);
    float*    inv_deg = (float*)w;    w += alignup(NN * 4);
    int*      bcnt    = (int*)w;      w += alignup(NB * 4);
    int*      bbase   = (int*)w;      w += alignup(NB * 4);
    int*      bcur    = (int*)w;      w += alignup(NB * 4);
    unsigned* ebuf    = (unsigned*)w; w += alignup((size_t)NE * 4);
    int*      col     = (int*)w;      w += alignup((size_t)NE * 4);
    float*    bufA    = (float*)w;    w += alignup((size_t)NN * 64 * 4);
    float*    bufB    = (float*)w;    w += alignup((size_t)NN * 64 * 4);
    float*    bufC    = (float*)w;    w += alignup((size_t)NN * 64 * 4);

    // ---- CSR build (bucketed counting sort) ----
    hipMemsetAsync(bcnt, 0, NB * sizeof(int), stream);
    k_bcount<<<1024, 256, 0, stream>>>(dst, bcnt);
    k_bscan<<<1, 256, 0, stream>>>(bcnt, bbase, bcur, row_ptr);
    k_bscatter<<<(NE + 4095) / 4096, 256, 0, stream>>>(src, dst, bcur, ebuf);
    k_bcsr<<<NB, 256, 0, stream>>>(ebuf, bbase, row_ptr, inv_deg, col);

    // ---- feature_pre: bufA = x @ W_pre.T + b_pre ----
    k_mm<128, 0, 64, false, false><<<(NN + 63) / 64, 256, 0, stream>>>(x, nullptr, W_pre, nullptr, b_pre, bufA);

    // ---- layer 1 ----
    k_agg<<<(NN * 64 + 255) / 256, 256, 0, stream>>>(bufA, row_ptr, col, inv_deg, bufB);
    k_mm<64, 64, 64, true, false><<<(NN + 63) / 64, 256, 0, stream>>>(bufB, bufA, Wl1, Wr1, bl1, bufC);

    // ---- layer 2 ----
    k_agg<<<(NN * 64 + 255) / 256, 256, 0, stream>>>(bufC, row_ptr, col, inv_deg, bufB);
    k_mm<64, 64, 64, true, false><<<(NN + 63) / 64, 256, 0, stream>>>(bufB, bufC, Wl2, Wr2, bl2, bufA);

    // ---- layer 3 (M=32) + fused L2 normalize ----
    k_agg<<<(NN * 64 + 255) / 256, 256, 0, stream>>>(bufA, row_ptr, col, inv_deg, bufB);
    k_mm<64, 64, 32, false, true><<<(NN + 63) / 64, 256, 0, stream>>>(bufB, bufA, Wl3, Wr3, bl3, out);
}

// Round 8
// 442.599 us; speedup vs baseline: 4.9062x; 1.2163x over previous
//
#include <hip/hip_runtime.h>

#define NN 100000
#define NE 1600000
#define NB 196      // dst buckets (dst >> 9), 512 nodes each
#define NPBK 512    // nodes per bucket

static inline size_t alignup(size_t x) { return (x + 255) & ~(size_t)255; }

// bf16 helpers (storage only; all math fp32)
__device__ __forceinline__ float bf_lo(unsigned u) { return __uint_as_float(u << 16); }
__device__ __forceinline__ float bf_hi(unsigned u) { return __uint_as_float(u & 0xFFFF0000u); }
__device__ __forceinline__ unsigned short f2bf(float f) {
    unsigned u = __float_as_uint(f);
    return (unsigned short)((u + 0x7FFFu + ((u >> 16) & 1u)) >> 16);  // RNE
}
__device__ __forceinline__ unsigned pack2(float a, float b) {
    return (unsigned)f2bf(a) | ((unsigned)f2bf(b) << 16);
}

// ---------------- bucket count: LDS histogram over 196 buckets ----------------
__global__ __launch_bounds__(256) void k_bcount(const int* __restrict__ dst,
                                                int* __restrict__ bcnt) {
    __shared__ int h[NB];
    int tid = threadIdx.x;
    for (int i = tid; i < NB; i += 256) h[i] = 0;
    __syncthreads();
    int i = blockIdx.x * 256 + tid;
    int stride = gridDim.x * 256;
    for (; i < NE; i += stride) atomicAdd(&h[dst[i] >> 9], 1);
    __syncthreads();
    for (int i2 = tid; i2 < NB; i2 += 256) {
        int c = h[i2];
        if (c) atomicAdd(&bcnt[i2], c);
    }
}

// ---------------- bucket scan (1 block): bases + cursors ----------------
__global__ __launch_bounds__(256) void k_bscan(const int* __restrict__ bcnt,
                                               int* __restrict__ bbase,
                                               int* __restrict__ bcur,
                                               int* __restrict__ row_ptr) {
    __shared__ int tmp[256];
    int tid = threadIdx.x;
    int v = (tid < NB) ? bcnt[tid] : 0;
    tmp[tid] = v;
    __syncthreads();
    for (int off = 1; off < 256; off <<= 1) {
        int t = (tid >= off) ? tmp[tid - off] : 0;
        __syncthreads();
        tmp[tid] += t;
        __syncthreads();
    }
    int excl = tmp[tid] - v;
    if (tid < NB) { bbase[tid] = excl; bcur[tid] = excl; }
    if (tid == 0) row_ptr[NN] = NE;
}

// ---------------- bucket scatter: pack (dstlocal,src), bucket-contiguous writes ----------------
#define EPT 16   // edges per thread; block chunk = 4096
__global__ __launch_bounds__(256) void k_bscatter(const int* __restrict__ src,
                                                  const int* __restrict__ dst,
                                                  int* __restrict__ bcur,
                                                  unsigned* __restrict__ ebuf) {
    __shared__ int h[NB], base[NB], pos[NB];
    int tid = threadIdx.x;
    for (int i = tid; i < NB; i += 256) h[i] = 0;
    __syncthreads();
    long e0 = (long)blockIdx.x * (256 * EPT);
    unsigned packed[EPT];
    int bk[EPT];
    #pragma unroll
    for (int j = 0; j < EPT; ++j) {
        long e = e0 + (long)j * 256 + tid;
        if (e < NE) {
            int s = src[e], d = dst[e];
            bk[j] = d >> 9;
            packed[j] = ((unsigned)(d & 511) << 17) | (unsigned)s;  // src < 2^17
            atomicAdd(&h[bk[j]], 1);
        } else bk[j] = -1;
    }
    __syncthreads();
    for (int i = tid; i < NB; i += 256) {
        int c = h[i];
        base[i] = c ? atomicAdd(&bcur[i], c) : 0;
        pos[i] = 0;
    }
    __syncthreads();
    #pragma unroll
    for (int j = 0; j < EPT; ++j) {
        if (bk[j] >= 0) {
            int p = atomicAdd(&pos[bk[j]], 1);
            ebuf[base[bk[j]] + p] = packed[j];
        }
    }
}

// ---------------- per-bucket CSR: hist + scan -> row_ptr/inv_deg, scatter col ----------------
__global__ __launch_bounds__(256) void k_bcsr(const unsigned* __restrict__ ebuf,
                                              const int* __restrict__ bbase,
                                              int* __restrict__ row_ptr,
                                              float* __restrict__ inv_deg,
                                              int* __restrict__ col) {
    __shared__ int h[NPBK];
    __shared__ int psum[256];
    int b = blockIdx.x;
    int tid = threadIdx.x;
    int begin = bbase[b];
    int end = (b + 1 < NB) ? bbase[b + 1] : NE;
    for (int i = tid; i < NPBK; i += 256) h[i] = 0;
    __syncthreads();
    for (int e = begin + tid; e < end; e += 256) atomicAdd(&h[ebuf[e] >> 17], 1);
    __syncthreads();
    int a0 = h[2 * tid], a1 = h[2 * tid + 1];
    psum[tid] = a0 + a1;
    __syncthreads();
    for (int off = 1; off < 256; off <<= 1) {
        int t = (tid >= off) ? psum[tid - off] : 0;
        __syncthreads();
        psum[tid] += t;
        __syncthreads();
    }
    int pexcl = psum[tid] - (a0 + a1);
    int eo0 = pexcl, eo1 = pexcl + a0;
    int n0 = b * NPBK + 2 * tid, n1 = n0 + 1;
    if (n0 < NN) { row_ptr[n0] = begin + eo0; inv_deg[n0] = 1.0f / (float)((a0 > 1) ? a0 : 1); }
    if (n1 < NN) { row_ptr[n1] = begin + eo1; inv_deg[n1] = 1.0f / (float)((a1 > 1) ? a1 : 1); }
    __syncthreads();
    h[2 * tid] = eo0;
    h[2 * tid + 1] = eo1;
    __syncthreads();
    for (int e = begin + tid; e < end; e += 256) {
        unsigned p = ebuf[e];
        int dl = p >> 17;
        int s = (int)(p & 0x1FFFFu);
        int q = atomicAdd(&h[dl], 1);
        col[begin + q] = s;
    }
}

// ---------------- LDS-staged tiled GEMM ----------------
// out[n][m] = cat(A1,A2)[n][:K] . cat(W1,W2)[m][:K] + bias[m]  (+relu / +L2-norm)
// ABF: A operands stored bf16 (unpacked to fp32 during LDS staging).
// OBF: output stored bf16 (RNE pack in epilogue). All accumulation fp32.
template <int K1, int K2, int M, bool RELU, bool NORM, bool ABF, bool OBF>
__global__ __launch_bounds__(256, 2) void k_mm(const void* __restrict__ A1v,
                                               const void* __restrict__ A2v,
                                               const float* __restrict__ W1,
                                               const float* __restrict__ W2,
                                               const float* __restrict__ bias,
                                               void* __restrict__ outv) {
    constexpr int K = K1 + K2;
    constexpr int MP = M + 4;
    constexpr int BN = 64;
    constexpr int MG = M / 4;          // m-groups (16 or 8)
    constexpr int NG = 256 / MG;       // node lanes (16 or 32)
    constexpr int R  = BN / NG;        // rows per thread (4 or 2)
    constexpr int S1 = K1 + 4;
    constexpr int S2 = (K2 > 0 ? K2 : 1) + 4;

    __shared__ float At1[BN * S1];
    __shared__ float At2[(K2 > 0) ? BN * S2 : 1];
    __shared__ float Wt[K * MP];
    __shared__ float ssq[NORM ? BN : 1];

    int tid = threadIdx.x;
    long nbase = (long)blockIdx.x * BN;

    // ---- stage weights: Wt[k][m] ----
    for (int idx = tid; idx < M * K; idx += 256) {
        int m = idx / K, k = idx % K;
        float v = (k < K1) ? W1[m * K1 + k] : W2[m * K2 + (k - K1)];
        Wt[k * MP + m] = v;
    }
    // ---- stage A tiles (coalesced row loads) ----
    if (ABF) {
        const unsigned short* A1 = (const unsigned short*)A1v;
        for (int i = tid; i < BN * (K1 / 8); i += 256) {
            int row = i / (K1 / 8);
            int c8 = i % (K1 / 8);
            long n = nbase + row;
            uint4 v = make_uint4(0u, 0u, 0u, 0u);
            if (n < NN) v = ((const uint4*)(A1 + n * K1))[c8];
            float4 lo4 = make_float4(bf_lo(v.x), bf_hi(v.x), bf_lo(v.y), bf_hi(v.y));
            float4 hi4 = make_float4(bf_lo(v.z), bf_hi(v.z), bf_lo(v.w), bf_hi(v.w));
            *(float4*)&At1[row * S1 + c8 * 8] = lo4;
            *(float4*)&At1[row * S1 + c8 * 8 + 4] = hi4;
        }
        if (K2 > 0) {
            const unsigned short* A2 = (const unsigned short*)A2v;
            for (int i = tid; i < BN * (K2 / 8); i += 256) {
                int row = i / (K2 / 8);
                int c8 = i % (K2 / 8);
                long n = nbase + row;
                uint4 v = make_uint4(0u, 0u, 0u, 0u);
                if (n < NN) v = ((const uint4*)(A2 + n * K2))[c8];
                float4 lo4 = make_float4(bf_lo(v.x), bf_hi(v.x), bf_lo(v.y), bf_hi(v.y));
                float4 hi4 = make_float4(bf_lo(v.z), bf_hi(v.z), bf_lo(v.w), bf_hi(v.w));
                *(float4*)&At2[row * S2 + c8 * 8] = lo4;
                *(float4*)&At2[row * S2 + c8 * 8 + 4] = hi4;
            }
        }
    } else {
        const float* A1 = (const float*)A1v;
        for (int i = tid; i < BN * (K1 / 4); i += 256) {
            int row = i / (K1 / 4);
            int c4 = i % (K1 / 4);
            long n = nbase + row;
            float4 v = make_float4(0.f, 0.f, 0.f, 0.f);
            if (n < NN) v = *(const float4*)(A1 + n * K1 + c4 * 4);
            *(float4*)&At1[row * S1 + c4 * 4] = v;
        }
    }
    if (NORM) { for (int i = tid; i < BN; i += 256) ssq[i] = 0.0f; }
    __syncthreads();

    int ng = tid % NG;
    int mg = tid / NG;
    int m0 = mg * 4;

    float4 bv = *(const float4*)&bias[m0];
    float acc[R][4];
    #pragma unroll
    for (int r = 0; r < R; ++r) {
        acc[r][0] = bv.x; acc[r][1] = bv.y; acc[r][2] = bv.z; acc[r][3] = bv.w;
    }

    #pragma unroll 4
    for (int k4 = 0; k4 < K1 / 4; ++k4) {
        float4 w0 = *(const float4*)&Wt[(4 * k4 + 0) * MP + m0];
        float4 w1 = *(const float4*)&Wt[(4 * k4 + 1) * MP + m0];
        float4 w2 = *(const float4*)&Wt[(4 * k4 + 2) * MP + m0];
        float4 w3 = *(const float4*)&Wt[(4 * k4 + 3) * MP + m0];
        #pragma unroll
        for (int r = 0; r < R; ++r) {
            float4 a = *(const float4*)&At1[(ng + NG * r) * S1 + 4 * k4];
            acc[r][0] += a.x * w0.x + a.y * w1.x + a.z * w2.x + a.w * w3.x;
            acc[r][1] += a.x * w0.y + a.y * w1.y + a.z * w2.y + a.w * w3.y;
            acc[r][2] += a.x * w0.z + a.y * w1.z + a.z * w2.z + a.w * w3.z;
            acc[r][3] += a.x * w0.w + a.y * w1.w + a.z * w2.w + a.w * w3.w;
        }
    }
    if (K2 > 0) {
        #pragma unroll 4
        for (int k4 = 0; k4 < K2 / 4; ++k4) {
            float4 w0 = *(const float4*)&Wt[(K1 + 4 * k4 + 0) * MP + m0];
            float4 w1 = *(const float4*)&Wt[(K1 + 4 * k4 + 1) * MP + m0];
            float4 w2 = *(const float4*)&Wt[(K1 + 4 * k4 + 2) * MP + m0];
            float4 w3 = *(const float4*)&Wt[(K1 + 4 * k4 + 3) * MP + m0];
            #pragma unroll
            for (int r = 0; r < R; ++r) {
                float4 a = *(const float4*)&At2[(ng + NG * r) * S2 + 4 * k4];
                acc[r][0] += a.x * w0.x + a.y * w1.x + a.z * w2.x + a.w * w3.x;
                acc[r][1] += a.x * w0.y + a.y * w1.y + a.z * w2.y + a.w * w3.y;
                acc[r][2] += a.x * w0.z + a.y * w1.z + a.z * w2.z + a.w * w3.z;
                acc[r][3] += a.x * w0.w + a.y * w1.w + a.z * w2.w + a.w * w3.w;
            }
        }
    }

    if (RELU) {
        #pragma unroll
        for (int r = 0; r < R; ++r)
            #pragma unroll
            for (int j = 0; j < 4; ++j) acc[r][j] = fmaxf(acc[r][j], 0.0f);
    }

    if (NORM) {
        #pragma unroll
        for (int r = 0; r < R; ++r) {
            float s = acc[r][0] * acc[r][0] + acc[r][1] * acc[r][1]
                    + acc[r][2] * acc[r][2] + acc[r][3] * acc[r][3];
            atomicAdd(&ssq[ng + NG * r], s);
        }
        __syncthreads();
    }

    #pragma unroll
    for (int r = 0; r < R; ++r) {
        long n = nbase + ng + NG * r;
        if (n >= NN) continue;
        float4 o;
        o.x = acc[r][0]; o.y = acc[r][1]; o.z = acc[r][2]; o.w = acc[r][3];
        if (NORM) {
            float sc = 1.0f / fmaxf(sqrtf(ssq[ng + NG * r]), 1e-12f);
            o.x *= sc; o.y *= sc; o.z *= sc; o.w *= sc;
        }
        if (OBF) {
            uint2 p;
            p.x = pack2(o.x, o.y);
            p.y = pack2(o.z, o.w);
            *(uint2*)((unsigned short*)outv + n * M + m0) = p;
        } else {
            *(float4*)((float*)outv + n * M + m0) = o;
        }
    }
}

// ---------------- neighbor aggregation (mean, bf16): 32 lanes/node, 2 feats/lane ----------------
__global__ __launch_bounds__(256) void k_agg16(const unsigned* __restrict__ H,
                                               const int* __restrict__ row_ptr,
                                               const int* __restrict__ col,
                                               const float* __restrict__ inv_deg,
                                               unsigned* __restrict__ AGG) {
    int gt = blockIdx.x * 256 + threadIdx.x;
    int n = gt >> 5;
    int l = gt & 31;
    if (n >= NN) return;
    int beg = row_ptr[n], end = row_ptr[n + 1];
    float a0 = 0.f, a1 = 0.f;
    int e = beg;
    for (; e + 3 < end; e += 4) {
        int s0 = col[e], s1 = col[e + 1], s2 = col[e + 2], s3 = col[e + 3];
        unsigned u0 = H[(long)s0 * 32 + l];
        unsigned u1 = H[(long)s1 * 32 + l];
        unsigned u2 = H[(long)s2 * 32 + l];
        unsigned u3 = H[(long)s3 * 32 + l];
        a0 += bf_lo(u0) + bf_lo(u1) + bf_lo(u2) + bf_lo(u3);
        a1 += bf_hi(u0) + bf_hi(u1) + bf_hi(u2) + bf_hi(u3);
    }
    for (; e < end; ++e) {
        unsigned u = H[(long)col[e] * 32 + l];
        a0 += bf_lo(u);
        a1 += bf_hi(u);
    }
    float w = inv_deg[n];
    AGG[(long)n * 32 + l] = pack2(a0 * w, a1 * w);
}

extern "C" void kernel_launch(void* const* d_in, const int* in_sizes, int n_in,
                              void* d_out, int out_size, void* d_ws, size_t ws_size,
                              hipStream_t stream) {
    const float* x      = (const float*)d_in[0];
    const int*   edges  = (const int*)d_in[1];
    const float* W_pre  = (const float*)d_in[2];
    const float* b_pre  = (const float*)d_in[3];
    const float* Wl1    = (const float*)d_in[4];
    const float* bl1    = (const float*)d_in[5];
    const float* Wr1    = (const float*)d_in[6];
    const float* Wl2    = (const float*)d_in[7];
    const float* bl2    = (const float*)d_in[8];
    const float* Wr2    = (const float*)d_in[9];
    const float* Wl3    = (const float*)d_in[10];
    const float* bl3    = (const float*)d_in[11];
    const float* Wr3    = (const float*)d_in[12];
    float* out = (float*)d_out;

    const int* src = edges;
    const int* dst = edges + NE;

    char* w = (char*)d_ws;
    int*      row_ptr = (int*)w;      w += alignup((NN + 1) * 4);
    float*    inv_deg = (float*)w;    w += alignup(NN * 4);
    int*      bcnt    = (int*)w;      w += alignup(NB * 4);
    int*      bbase   = (int*)w;      w += alignup(NB * 4);
    int*      bcur    = (int*)w;      w += alignup(NB * 4);
    unsigned* ebuf    = (unsigned*)w; w += alignup((size_t)NE * 4);
    int*      col     = (int*)w;      w += alignup((size_t)NE * 4);
    unsigned* bufA    = (unsigned*)w; w += alignup((size_t)NN * 64 * 2);  // bf16 [NN][64]
    unsigned* bufB    = (unsigned*)w; w += alignup((size_t)NN * 64 * 2);
    unsigned* bufC    = (unsigned*)w; w += alignup((size_t)NN * 64 * 2);

    // ---- CSR build (bucketed counting sort) ----
    hipMemsetAsync(bcnt, 0, NB * sizeof(int), stream);
    k_bcount<<<1024, 256, 0, stream>>>(dst, bcnt);
    k_bscan<<<1, 256, 0, stream>>>(bcnt, bbase, bcur, row_ptr);
    k_bscatter<<<(NE + 4095) / 4096, 256, 0, stream>>>(src, dst, bcur, ebuf);
    k_bcsr<<<NB, 256, 0, stream>>>(ebuf, bbase, row_ptr, inv_deg, col);

    // ---- feature_pre: bufA(bf16) = x @ W_pre.T + b_pre ----
    k_mm<128, 0, 64, false, false, false, true>
        <<<(NN + 63) / 64, 256, 0, stream>>>(x, nullptr, W_pre, nullptr, b_pre, bufA);

    // ---- layer 1 ----
    k_agg16<<<(NN * 32 + 255) / 256, 256, 0, stream>>>(bufA, row_ptr, col, inv_deg, bufB);
    k_mm<64, 64, 64, true, false, true, true>
        <<<(NN + 63) / 64, 256, 0, stream>>>(bufB, bufA, Wl1, Wr1, bl1, bufC);

    // ---- layer 2 ----
    k_agg16<<<(NN * 32 + 255) / 256, 256, 0, stream>>>(bufC, row_ptr, col, inv_deg, bufB);
    k_mm<64, 64, 64, true, false, true, true>
        <<<(NN + 63) / 64, 256, 0, stream>>>(bufB, bufC, Wl2, Wr2, bl2, bufA);

    // ---- layer 3 (M=32) + fused L2 normalize -> fp32 out ----
    k_agg16<<<(NN * 32 + 255) / 256, 256, 0, stream>>>(bufA, row_ptr, col, inv_deg, bufB);
    k_mm<64, 64, 32, false, true, true, false>
        <<<(NN + 63) / 64, 256, 0, stream>>>(bufB, bufA, Wl3, Wr3, bl3, out);
}

// Round 9
// 384.447 us; speedup vs baseline: 5.6483x; 1.1513x over previous
//
#include <hip/hip_runtime.h>

#define NN 100000
#define NE 1600000
#define NB 196      // dst buckets (dst >> 9), 512 nodes each
#define NPBK 512    // nodes per bucket

static inline size_t alignup(size_t x) { return (x + 255) & ~(size_t)255; }

typedef __attribute__((ext_vector_type(8))) short bfrag;   // 8 bf16 = 4 VGPRs
typedef __attribute__((ext_vector_type(4))) float f32x4v;  // MFMA acc

// bf16 helpers (storage only; all math fp32)
__device__ __forceinline__ float bf_lo(unsigned u) { return __uint_as_float(u << 16); }
__device__ __forceinline__ float bf_hi(unsigned u) { return __uint_as_float(u & 0xFFFF0000u); }
__device__ __forceinline__ unsigned short f2bf(float f) {
    unsigned u = __float_as_uint(f);
    return (unsigned short)((u + 0x7FFFu + ((u >> 16) & 1u)) >> 16);  // RNE
}
__device__ __forceinline__ unsigned pack2(float a, float b) {
    return (unsigned)f2bf(a) | ((unsigned)f2bf(b) << 16);
}

// ---------------- bucket count ----------------
__global__ __launch_bounds__(256) void k_bcount(const int* __restrict__ dst,
                                                int* __restrict__ bcnt) {
    __shared__ int h[NB];
    int tid = threadIdx.x;
    for (int i = tid; i < NB; i += 256) h[i] = 0;
    __syncthreads();
    int i = blockIdx.x * 256 + tid;
    int stride = gridDim.x * 256;
    for (; i < NE; i += stride) atomicAdd(&h[dst[i] >> 9], 1);
    __syncthreads();
    for (int i2 = tid; i2 < NB; i2 += 256) {
        int c = h[i2];
        if (c) atomicAdd(&bcnt[i2], c);
    }
}

// ---------------- bucket scan ----------------
__global__ __launch_bounds__(256) void k_bscan(const int* __restrict__ bcnt,
                                               int* __restrict__ bbase,
                                               int* __restrict__ bcur,
                                               int* __restrict__ row_ptr) {
    __shared__ int tmp[256];
    int tid = threadIdx.x;
    int v = (tid < NB) ? bcnt[tid] : 0;
    tmp[tid] = v;
    __syncthreads();
    for (int off = 1; off < 256; off <<= 1) {
        int t = (tid >= off) ? tmp[tid - off] : 0;
        __syncthreads();
        tmp[tid] += t;
        __syncthreads();
    }
    int excl = tmp[tid] - v;
    if (tid < NB) { bbase[tid] = excl; bcur[tid] = excl; }
    if (tid == 0) row_ptr[NN] = NE;
}

// ---------------- bucket scatter ----------------
#define EPT 16
__global__ __launch_bounds__(256) void k_bscatter(const int* __restrict__ src,
                                                  const int* __restrict__ dst,
                                                  int* __restrict__ bcur,
                                                  unsigned* __restrict__ ebuf) {
    __shared__ int h[NB], base[NB], pos[NB];
    int tid = threadIdx.x;
    for (int i = tid; i < NB; i += 256) h[i] = 0;
    __syncthreads();
    long e0 = (long)blockIdx.x * (256 * EPT);
    unsigned packed[EPT];
    int bk[EPT];
    #pragma unroll
    for (int j = 0; j < EPT; ++j) {
        long e = e0 + (long)j * 256 + tid;
        if (e < NE) {
            int s = src[e], d = dst[e];
            bk[j] = d >> 9;
            packed[j] = ((unsigned)(d & 511) << 17) | (unsigned)s;  // src < 2^17
            atomicAdd(&h[bk[j]], 1);
        } else bk[j] = -1;
    }
    __syncthreads();
    for (int i = tid; i < NB; i += 256) {
        int c = h[i];
        base[i] = c ? atomicAdd(&bcur[i], c) : 0;
        pos[i] = 0;
    }
    __syncthreads();
    #pragma unroll
    for (int j = 0; j < EPT; ++j) {
        if (bk[j] >= 0) {
            int p = atomicAdd(&pos[bk[j]], 1);
            ebuf[base[bk[j]] + p] = packed[j];
        }
    }
}

// ---------------- per-bucket CSR ----------------
__global__ __launch_bounds__(256) void k_bcsr(const unsigned* __restrict__ ebuf,
                                              const int* __restrict__ bbase,
                                              int* __restrict__ row_ptr,
                                              float* __restrict__ inv_deg,
                                              int* __restrict__ col) {
    __shared__ int h[NPBK];
    __shared__ int psum[256];
    int b = blockIdx.x;
    int tid = threadIdx.x;
    int begin = bbase[b];
    int end = (b + 1 < NB) ? bbase[b + 1] : NE;
    for (int i = tid; i < NPBK; i += 256) h[i] = 0;
    __syncthreads();
    for (int e = begin + tid; e < end; e += 256) atomicAdd(&h[ebuf[e] >> 17], 1);
    __syncthreads();
    int a0 = h[2 * tid], a1 = h[2 * tid + 1];
    psum[tid] = a0 + a1;
    __syncthreads();
    for (int off = 1; off < 256; off <<= 1) {
        int t = (tid >= off) ? psum[tid - off] : 0;
        __syncthreads();
        psum[tid] += t;
        __syncthreads();
    }
    int pexcl = psum[tid] - (a0 + a1);
    int eo0 = pexcl, eo1 = pexcl + a0;
    int n0 = b * NPBK + 2 * tid, n1 = n0 + 1;
    if (n0 < NN) { row_ptr[n0] = begin + eo0; inv_deg[n0] = 1.0f / (float)((a0 > 1) ? a0 : 1); }
    if (n1 < NN) { row_ptr[n1] = begin + eo1; inv_deg[n1] = 1.0f / (float)((a1 > 1) ? a1 : 1); }
    __syncthreads();
    h[2 * tid] = eo0;
    h[2 * tid + 1] = eo1;
    __syncthreads();
    for (int e = begin + tid; e < end; e += 256) {
        unsigned p = ebuf[e];
        int dl = p >> 17;
        int s = (int)(p & 0x1FFFFu);
        int q = atomicAdd(&h[dl], 1);
        col[begin + q] = s;
    }
}

// ---------------- MFMA GEMM ----------------
// out[n][m] = cat(A1,A2)[n][:128] . W[m][:128] + bias[m]  (+relu / +L2-norm)
// ABF=1: A1,A2 are bf16 [NN][64] each. ABF=0: A1 is fp32 [NN][128], hi/lo split (3 MFMAs).
// Weights always hi/lo split (fp32-equivalent). Accum fp32 in MFMA.
// Layouts (CDNA verified): A row=lane&15, B col=lane&15, k=(lane>>4)*8+j;
// D col=lane&15, row=(lane>>4)*4+reg.
template <int K1, int K2, int M, bool RELU, bool NORM, bool ABF, bool OBF>
__global__ __launch_bounds__(256, 2) void k_mfma(const void* __restrict__ A1v,
                                                 const void* __restrict__ A2v,
                                                 const float* __restrict__ W1,
                                                 const float* __restrict__ W2,
                                                 const float* __restrict__ bias,
                                                 void* __restrict__ outv) {
    constexpr int K = K1 + K2;
    static_assert(K == 128, "K must be 128");
    constexpr int NT = M / 16;       // 16-col tiles
    constexpr int SA = 136;          // padded bf16 row stride (conflict-free b128)
    constexpr int SW = 136;

    __shared__ __align__(16) unsigned short Ahi[64 * SA];
    __shared__ __align__(16) unsigned short Alo[ABF ? 1 : 64 * SA];
    __shared__ __align__(16) unsigned short Whi[M * SW];
    __shared__ __align__(16) unsigned short Wlo[M * SW];

    int tid = threadIdx.x;
    long nbase = (long)blockIdx.x * 64;

    // ---- stage weights, hi/lo split: logical W[m][k] (k<K1 from W1 else W2) ----
    for (int idx = tid; idx < M * 128; idx += 256) {
        int m = idx >> 7, k = idx & 127;
        float w = (K2 == 0 || k < K1) ? W1[m * K1 + k] : W2[m * K2 + (k - K1)];
        unsigned short hb = f2bf(w);
        float hf = __uint_as_float((unsigned)hb << 16);
        Whi[m * SW + k] = hb;
        Wlo[m * SW + k] = f2bf(w - hf);
    }
    // ---- stage A tile ----
    if (ABF) {
        const unsigned short* A1 = (const unsigned short*)A1v;
        const unsigned short* A2 = (const unsigned short*)A2v;
        for (int idx = tid; idx < 64 * 16; idx += 256) {   // 16 chunks of 8 bf16
            int row = idx >> 4, c8 = idx & 15;
            long n = nbase + row;
            uint4 v = make_uint4(0u, 0u, 0u, 0u);
            if (n < NN) v = (c8 < 8) ? ((const uint4*)(A1 + n * 64))[c8]
                                     : ((const uint4*)(A2 + n * 64))[c8 - 8];
            *(uint4*)&Ahi[row * SA + c8 * 8] = v;
        }
    } else {
        const float* A1 = (const float*)A1v;
        for (int idx = tid; idx < 64 * 32; idx += 256) {   // 32 chunks of 4 fp32
            int row = idx >> 5, c4 = idx & 31;
            long n = nbase + row;
            float4 v = make_float4(0.f, 0.f, 0.f, 0.f);
            if (n < NN) v = ((const float4*)(A1 + n * 128))[c4];
            ushort4 h, l;
            h.x = f2bf(v.x); l.x = f2bf(v.x - __uint_as_float((unsigned)h.x << 16));
            h.y = f2bf(v.y); l.y = f2bf(v.y - __uint_as_float((unsigned)h.y << 16));
            h.z = f2bf(v.z); l.z = f2bf(v.z - __uint_as_float((unsigned)h.z << 16));
            h.w = f2bf(v.w); l.w = f2bf(v.w - __uint_as_float((unsigned)h.w << 16));
            *(ushort4*)&Ahi[row * SA + c4 * 4] = h;
            *(ushort4*)&Alo[row * SA + c4 * 4] = l;
        }
    }
    __syncthreads();

    const int l = tid & 63, wv = tid >> 6;
    const int row0 = wv * 16;           // wave owns rows row0..row0+15
    const int mrow = l & 15, g = l >> 4;
    const int koff = g * 8;

    bfrag a[4], al[4];
    #pragma unroll
    for (int kk = 0; kk < 4; ++kk)
        a[kk] = *(const bfrag*)&Ahi[(row0 + mrow) * SA + kk * 32 + koff];
    if (!ABF) {
        #pragma unroll
        for (int kk = 0; kk < 4; ++kk)
            al[kk] = *(const bfrag*)&Alo[(row0 + mrow) * SA + kk * 32 + koff];
    }

    f32x4v acc[NT];
    #pragma unroll
    for (int c = 0; c < NT; ++c) {
        float bv = bias[c * 16 + mrow];
        acc[c][0] = bv; acc[c][1] = bv; acc[c][2] = bv; acc[c][3] = bv;
    }

    #pragma unroll
    for (int c = 0; c < NT; ++c) {
        #pragma unroll
        for (int kk = 0; kk < 4; ++kk) {
            bfrag bh = *(const bfrag*)&Whi[(c * 16 + mrow) * SW + kk * 32 + koff];
            bfrag bl = *(const bfrag*)&Wlo[(c * 16 + mrow) * SW + kk * 32 + koff];
            acc[c] = __builtin_amdgcn_mfma_f32_16x16x32_bf16(a[kk], bh, acc[c], 0, 0, 0);
            acc[c] = __builtin_amdgcn_mfma_f32_16x16x32_bf16(a[kk], bl, acc[c], 0, 0, 0);
            if (!ABF)
                acc[c] = __builtin_amdgcn_mfma_f32_16x16x32_bf16(al[kk], bh, acc[c], 0, 0, 0);
        }
    }

    if (RELU) {
        #pragma unroll
        for (int c = 0; c < NT; ++c)
            #pragma unroll
            for (int j = 0; j < 4; ++j) acc[c][j] = fmaxf(acc[c][j], 0.0f);
    }

    if (NORM) {
        // row r = row0 + g*4 + j; its M cols live in this lane's acc[c][j] across
        // the 16 lanes sharing g. Reduce within the 16-lane group.
        #pragma unroll
        for (int j = 0; j < 4; ++j) {
            float s = 0.f;
            #pragma unroll
            for (int c = 0; c < NT; ++c) s += acc[c][j] * acc[c][j];
            s += __shfl_xor(s, 1);
            s += __shfl_xor(s, 2);
            s += __shfl_xor(s, 4);
            s += __shfl_xor(s, 8);
            float sc = 1.0f / fmaxf(sqrtf(s), 1e-12f);
            long n = nbase + row0 + g * 4 + j;
            if (n < NN) {
                float* outf = (float*)outv;
                #pragma unroll
                for (int c = 0; c < NT; ++c)
                    outf[n * M + c * 16 + mrow] = acc[c][j] * sc;
            }
        }
    } else {
        #pragma unroll
        for (int j = 0; j < 4; ++j) {
            long n = nbase + row0 + g * 4 + j;
            if (n >= NN) continue;
            #pragma unroll
            for (int c = 0; c < NT; ++c) {
                if (OBF) ((unsigned short*)outv)[n * M + c * 16 + mrow] = f2bf(acc[c][j]);
                else     ((float*)outv)[n * M + c * 16 + mrow] = acc[c][j];
            }
        }
    }
}

// ---------------- neighbor aggregation (mean, bf16): 32 lanes/node ----------------
__global__ __launch_bounds__(256) void k_agg16(const unsigned* __restrict__ H,
                                               const int* __restrict__ row_ptr,
                                               const int* __restrict__ col,
                                               const float* __restrict__ inv_deg,
                                               unsigned* __restrict__ AGG) {
    int gt = blockIdx.x * 256 + threadIdx.x;
    int n = gt >> 5;
    int l = gt & 31;
    if (n >= NN) return;
    int beg = row_ptr[n], end = row_ptr[n + 1];
    float a0 = 0.f, a1 = 0.f;
    int e = beg;
    for (; e + 3 < end; e += 4) {
        int s0 = col[e], s1 = col[e + 1], s2 = col[e + 2], s3 = col[e + 3];
        unsigned u0 = H[(long)s0 * 32 + l];
        unsigned u1 = H[(long)s1 * 32 + l];
        unsigned u2 = H[(long)s2 * 32 + l];
        unsigned u3 = H[(long)s3 * 32 + l];
        a0 += bf_lo(u0) + bf_lo(u1) + bf_lo(u2) + bf_lo(u3);
        a1 += bf_hi(u0) + bf_hi(u1) + bf_hi(u2) + bf_hi(u3);
    }
    for (; e < end; ++e) {
        unsigned u = H[(long)col[e] * 32 + l];
        a0 += bf_lo(u);
        a1 += bf_hi(u);
    }
    float w = inv_deg[n];
    AGG[(long)n * 32 + l] = pack2(a0 * w, a1 * w);
}

extern "C" void kernel_launch(void* const* d_in, const int* in_sizes, int n_in,
                              void* d_out, int out_size, void* d_ws, size_t ws_size,
                              hipStream_t stream) {
    const float* x      = (const float*)d_in[0];
    const int*   edges  = (const int*)d_in[1];
    const float* W_pre  = (const float*)d_in[2];
    const float* b_pre  = (const float*)d_in[3];
    const float* Wl1    = (const float*)d_in[4];
    const float* bl1    = (const float*)d_in[5];
    const float* Wr1    = (const float*)d_in[6];
    const float* Wl2    = (const float*)d_in[7];
    const float* bl2    = (const float*)d_in[8];
    const float* Wr2    = (const float*)d_in[9];
    const float* Wl3    = (const float*)d_in[10];
    const float* bl3    = (const float*)d_in[11];
    const float* Wr3    = (const float*)d_in[12];
    float* out = (float*)d_out;

    const int* src = edges;
    const int* dst = edges + NE;

    char* w = (char*)d_ws;
    int*      row_ptr = (int*)w;      w += alignup((NN + 1) * 4);
    float*    inv_deg = (float*)w;    w += alignup(NN * 4);
    int*      bcnt    = (int*)w;      w += alignup(NB * 4);
    int*      bbase   = (int*)w;      w += alignup(NB * 4);
    int*      bcur    = (int*)w;      w += alignup(NB * 4);
    unsigned* ebuf    = (unsigned*)w; w += alignup((size_t)NE * 4);
    int*      col     = (int*)w;      w += alignup((size_t)NE * 4);
    unsigned short* bufA = (unsigned short*)w; w += alignup((size_t)NN * 64 * 2);  // bf16 [NN][64]
    unsigned short* bufB = (unsigned short*)w; w += alignup((size_t)NN * 64 * 2);
    unsigned short* bufC = (unsigned short*)w; w += alignup((size_t)NN * 64 * 2);

    // ---- CSR build (bucketed counting sort) ----
    hipMemsetAsync(bcnt, 0, NB * sizeof(int), stream);
    k_bcount<<<1024, 256, 0, stream>>>(dst, bcnt);
    k_bscan<<<1, 256, 0, stream>>>(bcnt, bbase, bcur, row_ptr);
    k_bscatter<<<(NE + 4095) / 4096, 256, 0, stream>>>(src, dst, bcur, ebuf);
    k_bcsr<<<NB, 256, 0, stream>>>(ebuf, bbase, row_ptr, inv_deg, col);

    const int GRID = (NN + 63) / 64;

    // ---- feature_pre: bufA(bf16) = x @ W_pre.T + b_pre  (x hi/lo split) ----
    k_mfma<128, 0, 64, false, false, false, true>
        <<<GRID, 256, 0, stream>>>(x, nullptr, W_pre, nullptr, b_pre, bufA);

    // ---- layer 1 ----
    k_agg16<<<(NN * 32 + 255) / 256, 256, 0, stream>>>((unsigned*)bufA, row_ptr, col, inv_deg, (unsigned*)bufB);
    k_mfma<64, 64, 64, true, false, true, true>
        <<<GRID, 256, 0, stream>>>(bufB, bufA, Wl1, Wr1, bl1, bufC);

    // ---- layer 2 ----
    k_agg16<<<(NN * 32 + 255) / 256, 256, 0, stream>>>((unsigned*)bufC, row_ptr, col, inv_deg, (unsigned*)bufB);
    k_mfma<64, 64, 64, true, false, true, true>
        <<<GRID, 256, 0, stream>>>(bufB, bufC, Wl2, Wr2, bl2, bufA);

    // ---- layer 3 (M=32) + fused L2 normalize -> fp32 out ----
    k_agg16<<<(NN * 32 + 255) / 256, 256, 0, stream>>>((unsigned*)bufA, row_ptr, col, inv_deg, (unsigned*)bufB);
    k_mfma<64, 64, 32, false, true, true, false>
        <<<GRID, 256, 0, stream>>>(bufB, bufA, Wl3, Wr3, bl3, out);
}